// Round 9
// baseline (353.561 us; speedup 1.0000x reference)
//
#include <hip/hip_runtime.h>
#include <hip/hip_bf16.h>
#include <math.h>
#include <stdint.h>

typedef __bf16 bf16x8 __attribute__((ext_vector_type(8)));
typedef __bf16 bf16x4 __attribute__((ext_vector_type(4)));
typedef float floatx4 __attribute__((ext_vector_type(4)));
typedef short shortx4 __attribute__((ext_vector_type(4)));

#define NQS   2048
#define NKVS  2048
#define NKV1  2049
#define DM    1024
#define NH    16
#define DHD   64
#define BATCH 2
#define ROWS  (BATCH * NQS)   // 4096

// async global->LDS, 16B per lane. LDS dest must be wave-uniform base + lane*16.
__device__ __forceinline__ void gld_lds16(const __bf16* gp, __bf16* lp) {
    __builtin_amdgcn_global_load_lds(
        (const __attribute__((address_space(1))) uint32_t*)(uintptr_t)gp,
        (__attribute__((address_space(3))) uint32_t*)(uintptr_t)lp,
        16, 0, 0);
}

// tanh-form GELU in exp2 domain
__device__ __forceinline__ float gelu_fast(float x) {
    const float u = x * x;
    const float e = __builtin_amdgcn_exp2f(x * (-2.3022077f + (-0.1029431f) * u));
    return x * __builtin_amdgcn_rcpf(1.0f + e);
}

// ---------------------------------------------------------------------------
// Fused LayerNorm for X and Y (f32 in) -> bf16 out.  grid 2*ROWS.
// ---------------------------------------------------------------------------
__global__ __launch_bounds__(256) void ln2_to_bf16(
    const float* __restrict__ X, const float* __restrict__ Y,
    const float* __restrict__ g0, const float* __restrict__ b0,
    const float* __restrict__ g0kv, const float* __restrict__ b0kv,
    __bf16* __restrict__ Xn, __bf16* __restrict__ Yn)
{
    int row = blockIdx.x;
    const float *src, *gamma, *beta; __bf16* dst;
    if (row < ROWS) { src = X; gamma = g0; beta = b0; dst = Xn; }
    else { row -= ROWS; src = Y; gamma = g0kv; beta = b0kv; dst = Yn; }
    const int tid = threadIdx.x;
    const float4 v = ((const float4*)(src + (size_t)row * DM))[tid];
    float s  = v.x + v.y + v.z + v.w;
    float sq = v.x * v.x + v.y * v.y + v.z * v.z + v.w * v.w;
    for (int off = 1; off < 64; off <<= 1) {
        s  += __shfl_xor(s, off);
        sq += __shfl_xor(sq, off);
    }
    __shared__ float red[8];
    const int wave = tid >> 6, lane = tid & 63;
    if (lane == 0) { red[wave * 2] = s; red[wave * 2 + 1] = sq; }
    __syncthreads();
    s  = red[0] + red[2] + red[4] + red[6];
    sq = red[1] + red[3] + red[5] + red[7];
    const float mu  = s * (1.0f / DM);
    const float var = sq * (1.0f / DM) - mu * mu;
    const float rs  = rsqrtf(var + 1e-5f);
    const float4 gv = ((const float4*)gamma)[tid];
    const float4 bv = ((const float4*)beta)[tid];
    bf16x4 o;
    o[0] = (__bf16)((v.x - mu) * rs * gv.x + bv.x);
    o[1] = (__bf16)((v.y - mu) * rs * gv.y + bv.y);
    o[2] = (__bf16)((v.z - mu) * rs * gv.z + bv.z);
    o[3] = (__bf16)((v.w - mu) * rs * gv.w + bv.w);
    *(bf16x4*)(dst + (size_t)row * DM + tid * 4) = o;
}

// ---------------------------------------------------------------------------
// Residual add + LayerNorm: Hres = X + O (f32 out), Hr = LN(Hres) (bf16 out)
// ---------------------------------------------------------------------------
__global__ __launch_bounds__(256) void resid_ln(
    const float* __restrict__ X, const __bf16* __restrict__ O,
    const float* __restrict__ gamma, const float* __restrict__ beta,
    float* __restrict__ Hres, __bf16* __restrict__ Hr)
{
    const int row = blockIdx.x;
    const int tid = threadIdx.x;
    const float4 xv = ((const float4*)(X + (size_t)row * DM))[tid];
    const bf16x4 ov = *(const bf16x4*)(O + (size_t)row * DM + tid * 4);
    float4 v;
    v.x = xv.x + (float)ov[0];
    v.y = xv.y + (float)ov[1];
    v.z = xv.z + (float)ov[2];
    v.w = xv.w + (float)ov[3];
    ((float4*)(Hres + (size_t)row * DM))[tid] = v;

    float s  = v.x + v.y + v.z + v.w;
    float sq = v.x * v.x + v.y * v.y + v.z * v.z + v.w * v.w;
    for (int off = 1; off < 64; off <<= 1) {
        s  += __shfl_xor(s, off);
        sq += __shfl_xor(sq, off);
    }
    __shared__ float red[8];
    const int wave = tid >> 6, lane = tid & 63;
    if (lane == 0) { red[wave * 2] = s; red[wave * 2 + 1] = sq; }
    __syncthreads();
    s  = red[0] + red[2] + red[4] + red[6];
    sq = red[1] + red[3] + red[5] + red[7];
    const float mu  = s * (1.0f / DM);
    const float var = sq * (1.0f / DM) - mu * mu;
    const float rs  = rsqrtf(var + 1e-5f);
    const float4 gv = ((const float4*)gamma)[tid];
    const float4 bv = ((const float4*)beta)[tid];
    bf16x4 o;
    o[0] = (__bf16)((v.x - mu) * rs * gv.x + bv.x);
    o[1] = (__bf16)((v.y - mu) * rs * gv.y + bv.y);
    o[2] = (__bf16)((v.z - mu) * rs * gv.z + bv.z);
    o[3] = (__bf16)((v.w - mu) * rs * gv.w + bv.w);
    *(bf16x4*)(Hr + (size_t)row * DM + tid * 4) = o;
}

// Fused transpose of the three 1024x1024 QKV weights (one launch, z picks W).
__global__ __launch_bounds__(256) void transpose3_f32_bf16(
    const float* __restrict__ Wq, const float* __restrict__ Wk,
    const float* __restrict__ Wv, __bf16* __restrict__ WqT,
    __bf16* __restrict__ WkT, __bf16* __restrict__ WvT)
{
    __shared__ float tile[32][33];
    const int z = blockIdx.z;
    const float* in = (z == 0) ? Wq : (z == 1) ? Wk : Wv;
    __bf16* out = (z == 0) ? WqT : (z == 1) ? WkT : WvT;
    const int c0 = blockIdx.x * 32, r0 = blockIdx.y * 32;
    const int tx = threadIdx.x, ty = threadIdx.y;
#pragma unroll
    for (int i = 0; i < 4; i++)
        tile[ty + i * 8][tx] = in[(size_t)(r0 + ty + i * 8) * DM + c0 + tx];
    __syncthreads();
#pragma unroll
    for (int i = 0; i < 4; i++)
        out[(size_t)(c0 + ty + i * 8) * DM + r0 + tx] = (__bf16)tile[tx][ty + i * 8];
}

// Fused transpose of W1 [1024][4096] and W2 [4096][1024] (z picks).
__global__ __launch_bounds__(256) void transpose_ffw(
    const float* __restrict__ W1, const float* __restrict__ W2,
    __bf16* __restrict__ W1T, __bf16* __restrict__ W2T)
{
    __shared__ float tile[32][33];
    const int z = blockIdx.z;
    const float* in; __bf16* out; int R, C, c0, r0;
    if (z == 0) { in = W1; out = W1T; R = DM; C = 4 * DM; c0 = blockIdx.x * 32; r0 = blockIdx.y * 32; }
    else        { in = W2; out = W2T; R = 4 * DM; C = DM; c0 = blockIdx.y * 32; r0 = blockIdx.x * 32; }
    const int tx = threadIdx.x, ty = threadIdx.y;
#pragma unroll
    for (int i = 0; i < 4; i++)
        tile[ty + i * 8][tx] = in[(size_t)(r0 + ty + i * 8) * C + c0 + tx];
    __syncthreads();
#pragma unroll
    for (int i = 0; i < 4; i++)
        out[(size_t)(c0 + ty + i * 8) * R + r0 + tx] = (__bf16)tile[tx][ty + i * 8];
}

// ---------------------------------------------------------------------------
// Fill null-K row (kv==2048) with null_k, and zero Vt pad columns [2048,2056)
// ---------------------------------------------------------------------------
__global__ __launch_bounds__(256) void fill_null(
    const float* __restrict__ null_k, __bf16* __restrict__ Kb,
    __bf16* __restrict__ Vt)
{
    const int i = blockIdx.x * 256 + threadIdx.x;
    if (i < BATCH * DM) {
        const int b = i >> 10, d = i & (DM - 1);
        Kb[((size_t)b * NKV1 + NKVS) * DM + d] = (__bf16)null_k[d];
    }
    if (i < BATCH * NH * DHD * 8) {  // 16384
        const int bhd = i >> 3, kvp = i & 7;
        Vt[(size_t)bhd * 2056 + 2048 + kvp] = (__bf16)0.0f;
    }
}

// ---------------------------------------------------------------------------
// 128x128-tile GEMM core (m97 structure + counted vmcnt):
// 256 threads (4 waves, 2Mx2N), per-wave 64x64 output, BK=32, 2-slot LDS
// dbuf (32 KB -> 4-5 blocks/CU, 4+ waves/SIMD: latency hidden by TLP).
// Per subtile: issue stage(s+1) FIRST, then counted vmcnt(4) + raw barrier
// (slot s visible; WAR-safe since the end-of-iter barrier proves all waves
// finished slot (s+1)&1's reads in iter s-1), ds_read + 16 MFMA, barrier.
// LDS source pre-swizzled: phys 16B chunk j of row r holds logical j^(r&3);
// reads XOR the same.
// ---------------------------------------------------------------------------
__device__ __forceinline__ void g128_loop(
    const __bf16* __restrict__ A, const __bf16* __restrict__ Bt,
    int Kst, int kbeg, int ns, int m0, int n0,
    __bf16* sa, __bf16* sb, floatx4 (&acc)[4][4])
{
    const int tid = threadIdx.x, lane = tid & 63;
    const int g = lane >> 4, c = lane & 15;
    const int wave = tid >> 6;
    const int wm = (wave >> 1) * 64, wn = (wave & 1) * 64;

    const int r = tid >> 2, j = tid & 3;          // r: 0..63
    const int jx = (j ^ (r & 3)) * 8;             // swizzled source chunk
    const __bf16* Ag = A  + (size_t)(m0 + r) * Kst + kbeg + jx;
    const __bf16* Bg = Bt + (size_t)(n0 + r) * Kst + kbeg + jx;
    __bf16* la = sa + tid * 8;                    // byte offset tid*16
    __bf16* lb = sb + tid * 8;

#define G128_STAGE(ss, koff) do {                                         \
    gld_lds16(Ag + (koff),                     la + (ss) * 4096);         \
    gld_lds16(Ag + (size_t)64 * Kst + (koff),  la + (ss) * 4096 + 2048);  \
    gld_lds16(Bg + (koff),                     lb + (ss) * 4096);         \
    gld_lds16(Bg + (size_t)64 * Kst + (koff),  lb + (ss) * 4096 + 2048);  \
} while (0)

    G128_STAGE(0, 0);

    const int rx = (g * 8) ^ ((c & 3) * 8);       // read-side XOR (elems)
    const __bf16* ra = sa + (wm + c) * 32;        // row base for A frags
    const __bf16* rb = sb + (wn + c) * 32;        // row base for B frags

    for (int s = 0; s < ns; s++) {
        if (s + 1 < ns) {
            G128_STAGE((s + 1) & 1, (s + 1) * 32);
            asm volatile("s_waitcnt vmcnt(4)" ::: "memory");  // slot s landed
        } else {
            asm volatile("s_waitcnt vmcnt(0)" ::: "memory");
        }
        __builtin_amdgcn_sched_barrier(0);
        __builtin_amdgcn_s_barrier();             // slot s visible block-wide
        asm volatile("" ::: "memory");

        const int ss = (s & 1) * 4096;
        bf16x8 af[4], bfr[4];
#pragma unroll
        for (int i = 0; i < 4; i++)
            af[i] = *(const bf16x8*)(ra + ss + i * 512 + rx);
#pragma unroll
        for (int jj = 0; jj < 4; jj++)
            bfr[jj] = *(const bf16x8*)(rb + ss + jj * 512 + rx);

        __builtin_amdgcn_s_setprio(1);
#pragma unroll
        for (int i = 0; i < 4; i++)
#pragma unroll
            for (int jj = 0; jj < 4; jj++)
                acc[i][jj] = __builtin_amdgcn_mfma_f32_16x16x32_bf16(
                    af[i], bfr[jj], acc[i][jj], 0, 0, 0);
        __builtin_amdgcn_s_setprio(0);
        __builtin_amdgcn_sched_barrier(0);
        __builtin_amdgcn_s_barrier();             // reads of slot s done
        asm volatile("" ::: "memory");
    }
#undef G128_STAGE
}

// XCD-bijective block swizzle (ntot % 8 == 0), 128-granular tiles.
template<int NX>
__device__ __forceinline__ void g128_decode(int bid, int ntot, int& m0, int& n0)
{
    const int cpx = ntot >> 3;
    const int l = (bid & 7) * cpx + (bid >> 3);
    m0 = (l / NX) * 128;
    n0 = (l % NX) * 128;
}

// MODE 0: bf16 flat [M][N] (+bias, optional GELU).  MODE 4: split-K f32
// partials at [z][M][N] (blockIdx.z = K-slice of K/4).
template<int MODE, int ACT, int NX>
__global__ __launch_bounds__(256, 4) void g128(
    const __bf16* __restrict__ A, const __bf16* __restrict__ Bt,
    const float* __restrict__ bias, void* __restrict__ outp,
    int M, int N, int K)
{
    __shared__ __bf16 SA[2][128][32];
    __shared__ __bf16 SB[2][128][32];
    int m0, n0;
    g128_decode<NX>(blockIdx.x, NX * (M >> 7), m0, n0);
    const int kbeg = (MODE == 4) ? blockIdx.z * (K >> 2) : 0;
    const int ns = ((MODE == 4) ? (K >> 2) : K) >> 5;

    floatx4 acc[4][4] = {};
    g128_loop(A, Bt, K, kbeg, ns, m0, n0, &SA[0][0][0], &SB[0][0][0], acc);

    const int tid = threadIdx.x, lane = tid & 63, wave = tid >> 6;
    const int g = lane >> 4, c = lane & 15;
    const int wm = (wave >> 1) * 64, wn = (wave & 1) * 64;

    __bf16* obf = (__bf16*)outp;
    float*  of  = (float*)outp;
#pragma unroll
    for (int i = 0; i < 4; i++) {
#pragma unroll
        for (int jj = 0; jj < 4; jj++) {
            const int row = m0 + wm + i * 16 + g * 4;
            const int col = n0 + wn + jj * 16 + c;
            const float bb = (MODE == 4) ? 0.0f : bias[col];
            float xs[4];
#pragma unroll
            for (int rr = 0; rr < 4; rr++) {
                float x = acc[i][jj][rr] + bb;
                if (ACT == 1) x = gelu_fast(x);
                xs[rr] = x;
            }
            if (MODE == 0) {
#pragma unroll
                for (int rr = 0; rr < 4; rr++)
                    obf[(size_t)(row + rr) * N + col] = (__bf16)xs[rr];
            } else if (MODE == 4) {
#pragma unroll
                for (int rr = 0; rr < 4; rr++)
                    of[((size_t)blockIdx.z * M + row + rr) * N + col] = xs[rr];
            }
        }
    }
}

// Fused Q/K/V projection on the 128-tile core.  grid (256,1,3) = 768 blocks.
__global__ __launch_bounds__(256, 4) void g128qkv(
    const __bf16* __restrict__ Xn, const __bf16* __restrict__ Yn,
    const __bf16* __restrict__ WqT, const __bf16* __restrict__ WkT,
    const __bf16* __restrict__ WvT,
    const float* __restrict__ bq, const float* __restrict__ bk,
    const float* __restrict__ bv,
    __bf16* __restrict__ Qbf, __bf16* __restrict__ Kbf,
    __bf16* __restrict__ Vt)
{
    __shared__ __bf16 SA[2][128][32];
    __shared__ __bf16 SB[2][128][32];
    const int z = blockIdx.z;
    const __bf16* A    = (z == 0) ? Xn  : Yn;
    const __bf16* Bt   = (z == 0) ? WqT : (z == 1) ? WkT : WvT;
    const float*  bias = (z == 0) ? bq  : (z == 1) ? bk  : bv;

    int m0, n0;
    g128_decode<8>(blockIdx.x, 256, m0, n0);

    floatx4 acc[4][4] = {};
    g128_loop(A, Bt, DM, 0, DM >> 5, m0, n0, &SA[0][0][0], &SB[0][0][0], acc);

    const int tid = threadIdx.x, lane = tid & 63, wave = tid >> 6;
    const int g = lane >> 4, c = lane & 15;
    const int wm = (wave >> 1) * 64, wn = (wave & 1) * 64;

#pragma unroll
    for (int i = 0; i < 4; i++) {
#pragma unroll
        for (int jj = 0; jj < 4; jj++) {
            const int row = m0 + wm + i * 16 + g * 4;
            const int col = n0 + wn + jj * 16 + c;
            const float bb = bias[col];
            float xs[4];
#pragma unroll
            for (int rr = 0; rr < 4; rr++) xs[rr] = acc[i][jj][rr] + bb;
            if (z == 0) {
#pragma unroll
                for (int rr = 0; rr < 4; rr++)
                    Qbf[(size_t)(row + rr) * DM + col] = (__bf16)xs[rr];
            } else if (z == 1) {
#pragma unroll
                for (int rr = 0; rr < 4; rr++) {
                    const int r2 = row + rr;
                    Kbf[(size_t)(r2 + (r2 >> 11)) * DM + col] = (__bf16)xs[rr];
                }
            } else {
                const int b  = row >> 11;
                const int kv = row & 2047;
                const size_t base =
                    ((size_t)((b * NH + (col >> 6)) * DHD + (col & 63))) * 2056 + kv;
                bf16x4 pk;
                pk[0] = (__bf16)xs[0]; pk[1] = (__bf16)xs[1];
                pk[2] = (__bf16)xs[2]; pk[3] = (__bf16)xs[3];
                *(bf16x4*)(Vt + base) = pk;
            }
        }
    }
}

// ---------------------------------------------------------------------------
// FF2 split-K reduction: out = sum_z partials[z] + bias + Hres.  float4/thread.
// ---------------------------------------------------------------------------
__global__ __launch_bounds__(256) void ff2_reduce(
    const float* __restrict__ part, const float* __restrict__ bias,
    const float* __restrict__ Hres, float* __restrict__ out)
{
    const size_t f4 = (size_t)blockIdx.x * 256 + threadIdx.x;  // float4 index
    const int c4 = (int)(f4 & (DM / 4 - 1));
    const size_t stride4 = (size_t)ROWS * DM / 4;
    float4 a = ((const float4*)part)[f4];
    const float4 p1 = ((const float4*)part)[f4 + stride4];
    const float4 p2 = ((const float4*)part)[f4 + 2 * stride4];
    const float4 p3 = ((const float4*)part)[f4 + 3 * stride4];
    const float4 b  = ((const float4*)bias)[c4];
    const float4 hr = ((const float4*)Hres)[f4];
    a.x += p1.x + p2.x + p3.x + b.x + hr.x;
    a.y += p1.y + p2.y + p3.y + b.y + hr.y;
    a.z += p1.z + p2.z + p3.z + b.z + hr.z;
    a.w += p1.w + p2.w + p3.w + b.w + hr.w;
    ((float4*)out)[f4] = a;
}

// ---------------------------------------------------------------------------
// Flash attention (round-8 proven): 128 q/block, 32 q/wave; gld_lds
// XOR-swizzled staging; 4-slot ring, 2 tiles per barrier; v_perm pack;
// ones-MFMA denominator; XCD-local heads.
// ---------------------------------------------------------------------------
__global__ __launch_bounds__(256, 2) void attn_kernel(
    const __bf16* __restrict__ Q, const __bf16* __restrict__ Kb,
    const __bf16* __restrict__ Vt, __bf16* __restrict__ O)
{
    __shared__ __bf16 Ks[4][64][64];   // [kv][d]   32 KB
    __shared__ __bf16 Vs[4][64][64];   // [d][kv]   32 KB

    const int tid = threadIdx.x, lane = tid & 63, w = tid >> 6;
    const int g = lane >> 4, c = lane & 15;

    const int hw   = blockIdx.x;
    const int slot = hw >> 3;
    const int hb   = (hw & 7) | ((slot >> 4) << 3);   // 0..31
    const int h = hb & 15, b = hb >> 4;
    const int q0w = (slot & 15) * 128 + w * 32;

    const float QSC = 0.03125f * 1.44269504088896f;
    bf16x8 qf[2][2];
#pragma unroll
    for (int qt = 0; qt < 2; qt++) {
        const __bf16* Qbase = Q + ((size_t)(b * NQS + q0w + qt * 16 + c)) * DM + h * DHD;
        qf[qt][0] = *(const bf16x8*)(Qbase + g * 8);
        qf[qt][1] = *(const bf16x8*)(Qbase + 32 + g * 8);
#pragma unroll
        for (int e = 0; e < 8; e++) {
            qf[qt][0][e] = (__bf16)((float)qf[qt][0][e] * QSC);
            qf[qt][1][e] = (__bf16)((float)qf[qt][1][e] * QSC);
        }
    }

    // ones fragment for the denominator MFMA (bf16 1.0 = 0x3F80)
    shortx4 ones;
    ones[0] = ones[1] = ones[2] = ones[3] = (short)0x3F80;

    floatx4 dacc[2] = {};        // denominator accumulators (rows identical)
    floatx4 oacc[2][4] = {};

    const int srow = tid >> 3;                    // LDS row 0..31 (and +32)
    const int schk = (tid & 7) ^ (srow & 7);      // swizzled 16B source chunk
    const __bf16* Kg  = Kb + (size_t)b * NKV1 * DM + h * DHD + schk * 8;
    const __bf16* Vg  = Vt + ((size_t)(b * NH + h) * DHD + srow) * 2056;
    const __bf16* Vg2 = Vg + (size_t)32 * 2056;
    const int vcol0 = schk * 8;

    auto stage = [&](int p, int kv0, bool tail) {
        __bf16* kd0 = &Ks[p][0][0]  + tid * 8;
        __bf16* kd1 = &Ks[p][32][0] + tid * 8;
        __bf16* vd0 = &Vs[p][0][0]  + tid * 8;
        __bf16* vd1 = &Vs[p][32][0] + tid * 8;
        if (!tail) {
            gld_lds16(Kg + (size_t)(kv0 + srow) * DM, kd0);
            gld_lds16(Kg + (size_t)(kv0 + srow + 32) * DM, kd1);
            gld_lds16(Vg + kv0 + vcol0, vd0);
            gld_lds16(Vg2 + kv0 + vcol0, vd1);
        } else {
            const int r0 = min(kv0 + srow, NKVS);
            const int r1 = min(kv0 + srow + 32, NKVS);
            const int vc = min(kv0 + vcol0, NKVS);
            gld_lds16(Kg + (size_t)r0 * DM, kd0);
            gld_lds16(Kg + (size_t)r1 * DM, kd1);
            gld_lds16(Vg + vc, vd0);
            gld_lds16(Vg2 + vc, vd1);
        }
    };

    auto compute = [&](int p, int kv0, bool tail) {
        floatx4 s[2][4];
#pragma unroll
        for (int qt = 0; qt < 2; qt++)
#pragma unroll
            for (int kvt = 0; kvt < 4; kvt++)
#pragma unroll
                for (int r = 0; r < 4; r++) s[qt][kvt][r] = -6.0f;

        const int sw = c & 7;
        __builtin_amdgcn_s_setprio(1);
#pragma unroll
        for (int kvt = 0; kvt < 4; kvt++) {
            const bf16x8 kf0 = *(const bf16x8*)&Ks[p][kvt * 16 + c][(g ^ sw) * 8];
            const bf16x8 kf1 = *(const bf16x8*)&Ks[p][kvt * 16 + c][((4 | g) ^ sw) * 8];
#pragma unroll
            for (int qt = 0; qt < 2; qt++) {
                s[qt][kvt] = __builtin_amdgcn_mfma_f32_16x16x32_bf16(kf0, qf[qt][0], s[qt][kvt], 0, 0, 0);
                s[qt][kvt] = __builtin_amdgcn_mfma_f32_16x16x32_bf16(kf1, qf[qt][1], s[qt][kvt], 0, 0, 0);
            }
        }
        __builtin_amdgcn_s_setprio(0);

        if (tail) {
#pragma unroll
            for (int qt = 0; qt < 2; qt++)
#pragma unroll
                for (int kvt = 0; kvt < 4; kvt++)
#pragma unroll
                    for (int r = 0; r < 4; r++)
                        if (kv0 + kvt * 16 + g * 4 + r >= NKV1) s[qt][kvt][r] = -1e30f;
        }

        // p = exp2(s); pack to bf16 by truncation via v_perm (1 op per word)
        shortx4 pf[2][4];
#pragma unroll
        for (int qt = 0; qt < 2; qt++)
#pragma unroll
            for (int kvt = 0; kvt < 4; kvt++) {
                const unsigned u0 = __builtin_bit_cast(unsigned, __builtin_amdgcn_exp2f(s[qt][kvt][0]));
                const unsigned u1 = __builtin_bit_cast(unsigned, __builtin_amdgcn_exp2f(s[qt][kvt][1]));
                const unsigned u2 = __builtin_bit_cast(unsigned, __builtin_amdgcn_exp2f(s[qt][kvt][2]));
                const unsigned u3 = __builtin_bit_cast(unsigned, __builtin_amdgcn_exp2f(s[qt][kvt][3]));
                unsigned pk0 = __builtin_amdgcn_perm(u1, u0, 0x07060302u);
                unsigned pk1 = __builtin_amdgcn_perm(u3, u2, 0x07060302u);
                unsigned long long pk = ((unsigned long long)pk1 << 32) | pk0;
                pf[qt][kvt] = __builtin_bit_cast(shortx4, pk);
            }

        // O^T += V^T P^T ; denominator via ones-row MFMA
        __builtin_amdgcn_s_setprio(1);
#pragma unroll
        for (int kvt = 0; kvt < 4; kvt++) {
            shortx4 vfr[4];
#pragma unroll
            for (int dt = 0; dt < 4; dt++) {
                const int slotp = (kvt * 2 + (g >> 1)) ^ sw;
                vfr[dt] = *(const shortx4*)&Vs[p][dt * 16 + c][slotp * 8 + (g & 1) * 4];
            }
#pragma unroll
            for (int dt = 0; dt < 4; dt++)
#pragma unroll
                for (int qt = 0; qt < 2; qt++)
                    oacc[qt][dt] = __builtin_amdgcn_mfma_f32_16x16x16bf16_1k(
                        vfr[dt], pf[qt][kvt], oacc[qt][dt], 0, 0, 0);
#pragma unroll
            for (int qt = 0; qt < 2; qt++)
                dacc[qt] = __builtin_amdgcn_mfma_f32_16x16x16bf16_1k(
                    ones, pf[qt][kvt], dacc[qt], 0, 0, 0);
        }
        __builtin_amdgcn_s_setprio(0);
    };

    // 4-slot ring, 2 tiles per barrier period.  Tiles 0..32 (32 = tail).
    stage(0, 0, false);
    stage(1, 64, false);
    __syncthreads();
    for (int it = 0; it < 32; it += 2) {
        stage((it + 2) & 3, (it + 2) * 64, (it + 2) == 32);
        if (it + 3 <= 32) stage((it + 3) & 3, (it + 3) * 64, false);
        compute(it & 3, it * 64, false);
        compute((it + 1) & 3, (it + 1) * 64, false);
        __syncthreads();                 // staged tiles visible; reads done
    }
    compute(0, 2048, true);              // tail tile (32) in slot 0

#pragma unroll
    for (int qt = 0; qt < 2; qt++) {
        const float inv_l = 1.0f / dacc[qt][0];
        __bf16* Ob = O + ((size_t)(b * NQS + q0w + qt * 16 + c)) * DM + h * DHD;
#pragma unroll
        for (int dt = 0; dt < 4; dt++) {
            bf16x4 ob;
#pragma unroll
            for (int r = 0; r < 4; r++) ob[r] = (__bf16)(oacc[qt][dt][r] * inv_l);
            *(bf16x4*)(Ob + dt * 16 + g * 4) = ob;
        }
    }
}

// ---------------------------------------------------------------------------
extern "C" void kernel_launch(void* const* d_in, const int* in_sizes, int n_in,
                              void* d_out, int out_size, void* d_ws, size_t ws_size,
                              hipStream_t stream)
{
    const float* X      = (const float*)d_in[0];
    const float* Y      = (const float*)d_in[1];
    const float* Wq     = (const float*)d_in[2];
    const float* bq     = (const float*)d_in[3];
    const float* Wk     = (const float*)d_in[4];
    const float* bk     = (const float*)d_in[5];
    const float* Wv     = (const float*)d_in[6];
    const float* bv     = (const float*)d_in[7];
    const float* null_k = (const float*)d_in[8];
    const float* g0     = (const float*)d_in[9];
    const float* b0     = (const float*)d_in[10];
    const float* g0kv   = (const float*)d_in[11];
    const float* b0kv   = (const float*)d_in[12];
    const float* g1     = (const float*)d_in[13];
    const float* b1     = (const float*)d_in[14];
    const float* W1     = (const float*)d_in[15];
    const float* bf1    = (const float*)d_in[16];
    const float* W2     = (const float*)d_in[17];
    const float* bf2    = (const float*)d_in[18];
    float* out = (float*)d_out;

    // workspace carve (bytes).  Persistent-through-FF2 buffers FIRST so the
    // tail region (dead by FF2 time) can be reused for split-K partials.
    char* p = (char*)d_ws;
    __bf16* W2T  = (__bf16*)p; p += (size_t)4 * DM * DM * 2;          // [1024][4096]
    float*  Hres = (float*)p;  p += (size_t)ROWS * DM * 4;
    __bf16* Gbf  = (__bf16*)p; p += (size_t)ROWS * 4 * DM * 2;
    char* scratch = p;                                                // dead by FF2
    __bf16* Xn   = (__bf16*)p; p += (size_t)ROWS * DM * 2;
    __bf16* Yn   = (__bf16*)p; p += (size_t)ROWS * DM * 2;
    __bf16* WqT  = (__bf16*)p; p += (size_t)DM * DM * 2;
    __bf16* WkT  = (__bf16*)p; p += (size_t)DM * DM * 2;
    __bf16* WvT  = (__bf16*)p; p += (size_t)DM * DM * 2;
    __bf16* W1T  = (__bf16*)p; p += (size_t)4 * DM * DM * 2;          // [4096][1024]
    __bf16* Qbf  = (__bf16*)p; p += (size_t)ROWS * DM * 2;
    __bf16* Kbf  = (__bf16*)p; p += (size_t)BATCH * NKV1 * DM * 2;
    __bf16* Vt   = (__bf16*)p; p += (size_t)BATCH * NH * DHD * 2056 * 2;
    __bf16* Obf  = (__bf16*)p; p += (size_t)ROWS * DM * 2;
    __bf16* Hr   = (__bf16*)p; p += (size_t)ROWS * DM * 2;
    float* Part  = (float*)scratch;  // FF2 partials: 4 x ROWS x DM f32 = 67 MB

    // 1. LayerNorms (fused X+Y, one launch)
    ln2_to_bf16<<<2 * ROWS, 256, 0, stream>>>(X, Y, g0, b0, g0kv, b0kv, Xn, Yn);

    // 2. weight transposes (f32 -> bf16, W^T), two launches total
    transpose3_f32_bf16<<<dim3(DM / 32, DM / 32, 3), dim3(32, 8), 0, stream>>>(
        Wq, Wk, Wv, WqT, WkT, WvT);
    transpose_ffw<<<dim3(128, 32, 2), dim3(32, 8), 0, stream>>>(W1, W2, W1T, W2T);

    // 3. fused Q/K/V projections on the 128-tile core (768 blocks = 3/CU)
    g128qkv<<<dim3(256, 1, 3), 256, 0, stream>>>(
        Xn, Yn, WqT, WkT, WvT, bq, bk, bv, Qbf, Kbf, Vt);
    fill_null<<<64, 256, 0, stream>>>(null_k, Kbf, Vt);

    // 4. attention (4-slot ring, 2 tiles/barrier, XCD-local heads)
    attn_kernel<<<dim3(512), 256, 0, stream>>>(Qbf, Kbf, Vt, Obf);

    // 5. residual + LN
    resid_ln<<<ROWS, 256, 0, stream>>>(X, Obf, g1, b1, Hres, Hr);

    // 6. FFN: FF1 (1024 blocks = 4/CU), FF2 split-K=4 (1024 blocks), reduce
    g128<0, 1, 32><<<1024, 256, 0, stream>>>(
        Hr, W1T, bf1, (void*)Gbf, ROWS, 4 * DM, DM);
    g128<4, 0, 8><<<dim3(256, 1, 4), 256, 0, stream>>>(
        Gbf, W2T, bf2, (void*)Part, ROWS, DM, 4 * DM);
    ff2_reduce<<<ROWS * DM / 1024, 256, 0, stream>>>(Part, bf2, Hres, out);
}

// Round 10
// 343.606 us; speedup vs baseline: 1.0290x; 1.0290x over previous
//
#include <hip/hip_runtime.h>
#include <hip/hip_bf16.h>
#include <math.h>
#include <stdint.h>

typedef __bf16 bf16x8 __attribute__((ext_vector_type(8)));
typedef __bf16 bf16x4 __attribute__((ext_vector_type(4)));
typedef float floatx4 __attribute__((ext_vector_type(4)));
typedef short shortx4 __attribute__((ext_vector_type(4)));

#define NQS   2048
#define NKVS  2048
#define NKV1  2049
#define DM    1024
#define NH    16
#define DHD   64
#define BATCH 2
#define ROWS  (BATCH * NQS)   // 4096

// async global->LDS, 16B per lane. LDS dest must be wave-uniform base + lane*16.
__device__ __forceinline__ void gld_lds16(const __bf16* gp, __bf16* lp) {
    __builtin_amdgcn_global_load_lds(
        (const __attribute__((address_space(1))) uint32_t*)(uintptr_t)gp,
        (__attribute__((address_space(3))) uint32_t*)(uintptr_t)lp,
        16, 0, 0);
}

// tanh-form GELU in exp2 domain
__device__ __forceinline__ float gelu_fast(float x) {
    const float u = x * x;
    const float e = __builtin_amdgcn_exp2f(x * (-2.3022077f + (-0.1029431f) * u));
    return x * __builtin_amdgcn_rcpf(1.0f + e);
}

// ---------------------------------------------------------------------------
// Fused LayerNorm for X and Y (f32 in) -> bf16 out.  grid 2*ROWS.
// ---------------------------------------------------------------------------
__global__ __launch_bounds__(256) void ln2_to_bf16(
    const float* __restrict__ X, const float* __restrict__ Y,
    const float* __restrict__ g0, const float* __restrict__ b0,
    const float* __restrict__ g0kv, const float* __restrict__ b0kv,
    __bf16* __restrict__ Xn, __bf16* __restrict__ Yn)
{
    int row = blockIdx.x;
    const float *src, *gamma, *beta; __bf16* dst;
    if (row < ROWS) { src = X; gamma = g0; beta = b0; dst = Xn; }
    else { row -= ROWS; src = Y; gamma = g0kv; beta = b0kv; dst = Yn; }
    const int tid = threadIdx.x;
    const float4 v = ((const float4*)(src + (size_t)row * DM))[tid];
    float s  = v.x + v.y + v.z + v.w;
    float sq = v.x * v.x + v.y * v.y + v.z * v.z + v.w * v.w;
    for (int off = 1; off < 64; off <<= 1) {
        s  += __shfl_xor(s, off);
        sq += __shfl_xor(sq, off);
    }
    __shared__ float red[8];
    const int wave = tid >> 6, lane = tid & 63;
    if (lane == 0) { red[wave * 2] = s; red[wave * 2 + 1] = sq; }
    __syncthreads();
    s  = red[0] + red[2] + red[4] + red[6];
    sq = red[1] + red[3] + red[5] + red[7];
    const float mu  = s * (1.0f / DM);
    const float var = sq * (1.0f / DM) - mu * mu;
    const float rs  = rsqrtf(var + 1e-5f);
    const float4 gv = ((const float4*)gamma)[tid];
    const float4 bv = ((const float4*)beta)[tid];
    bf16x4 o;
    o[0] = (__bf16)((v.x - mu) * rs * gv.x + bv.x);
    o[1] = (__bf16)((v.y - mu) * rs * gv.y + bv.y);
    o[2] = (__bf16)((v.z - mu) * rs * gv.z + bv.z);
    o[3] = (__bf16)((v.w - mu) * rs * gv.w + bv.w);
    *(bf16x4*)(dst + (size_t)row * DM + tid * 4) = o;
}

// ---------------------------------------------------------------------------
// Residual add + LayerNorm: Hres = X + O (f32 out), Hr = LN(Hres) (bf16 out)
// ---------------------------------------------------------------------------
__global__ __launch_bounds__(256) void resid_ln(
    const float* __restrict__ X, const __bf16* __restrict__ O,
    const float* __restrict__ gamma, const float* __restrict__ beta,
    float* __restrict__ Hres, __bf16* __restrict__ Hr)
{
    const int row = blockIdx.x;
    const int tid = threadIdx.x;
    const float4 xv = ((const float4*)(X + (size_t)row * DM))[tid];
    const bf16x4 ov = *(const bf16x4*)(O + (size_t)row * DM + tid * 4);
    float4 v;
    v.x = xv.x + (float)ov[0];
    v.y = xv.y + (float)ov[1];
    v.z = xv.z + (float)ov[2];
    v.w = xv.w + (float)ov[3];
    ((float4*)(Hres + (size_t)row * DM))[tid] = v;

    float s  = v.x + v.y + v.z + v.w;
    float sq = v.x * v.x + v.y * v.y + v.z * v.z + v.w * v.w;
    for (int off = 1; off < 64; off <<= 1) {
        s  += __shfl_xor(s, off);
        sq += __shfl_xor(sq, off);
    }
    __shared__ float red[8];
    const int wave = tid >> 6, lane = tid & 63;
    if (lane == 0) { red[wave * 2] = s; red[wave * 2 + 1] = sq; }
    __syncthreads();
    s  = red[0] + red[2] + red[4] + red[6];
    sq = red[1] + red[3] + red[5] + red[7];
    const float mu  = s * (1.0f / DM);
    const float var = sq * (1.0f / DM) - mu * mu;
    const float rs  = rsqrtf(var + 1e-5f);
    const float4 gv = ((const float4*)gamma)[tid];
    const float4 bv = ((const float4*)beta)[tid];
    bf16x4 o;
    o[0] = (__bf16)((v.x - mu) * rs * gv.x + bv.x);
    o[1] = (__bf16)((v.y - mu) * rs * gv.y + bv.y);
    o[2] = (__bf16)((v.z - mu) * rs * gv.z + bv.z);
    o[3] = (__bf16)((v.w - mu) * rs * gv.w + bv.w);
    *(bf16x4*)(Hr + (size_t)row * DM + tid * 4) = o;
}

// Fused transpose of the three 1024x1024 QKV weights (one launch, z picks W).
__global__ __launch_bounds__(256) void transpose3_f32_bf16(
    const float* __restrict__ Wq, const float* __restrict__ Wk,
    const float* __restrict__ Wv, __bf16* __restrict__ WqT,
    __bf16* __restrict__ WkT, __bf16* __restrict__ WvT)
{
    __shared__ float tile[32][33];
    const int z = blockIdx.z;
    const float* in = (z == 0) ? Wq : (z == 1) ? Wk : Wv;
    __bf16* out = (z == 0) ? WqT : (z == 1) ? WkT : WvT;
    const int c0 = blockIdx.x * 32, r0 = blockIdx.y * 32;
    const int tx = threadIdx.x, ty = threadIdx.y;
#pragma unroll
    for (int i = 0; i < 4; i++)
        tile[ty + i * 8][tx] = in[(size_t)(r0 + ty + i * 8) * DM + c0 + tx];
    __syncthreads();
#pragma unroll
    for (int i = 0; i < 4; i++)
        out[(size_t)(c0 + ty + i * 8) * DM + r0 + tx] = (__bf16)tile[tx][ty + i * 8];
}

// Fused transpose of W1 [1024][4096] and W2 [4096][1024] (z picks).
__global__ __launch_bounds__(256) void transpose_ffw(
    const float* __restrict__ W1, const float* __restrict__ W2,
    __bf16* __restrict__ W1T, __bf16* __restrict__ W2T)
{
    __shared__ float tile[32][33];
    const int z = blockIdx.z;
    const float* in; __bf16* out; int R, C, c0, r0;
    if (z == 0) { in = W1; out = W1T; R = DM; C = 4 * DM; c0 = blockIdx.x * 32; r0 = blockIdx.y * 32; }
    else        { in = W2; out = W2T; R = 4 * DM; C = DM; c0 = blockIdx.y * 32; r0 = blockIdx.x * 32; }
    const int tx = threadIdx.x, ty = threadIdx.y;
#pragma unroll
    for (int i = 0; i < 4; i++)
        tile[ty + i * 8][tx] = in[(size_t)(r0 + ty + i * 8) * C + c0 + tx];
    __syncthreads();
#pragma unroll
    for (int i = 0; i < 4; i++)
        out[(size_t)(c0 + ty + i * 8) * R + r0 + tx] = (__bf16)tile[tx][ty + i * 8];
}

// ---------------------------------------------------------------------------
// Fill null-K row (kv==2048) with null_k, and zero Vt pad columns [2048,2056)
// ---------------------------------------------------------------------------
__global__ __launch_bounds__(256) void fill_null(
    const float* __restrict__ null_k, __bf16* __restrict__ Kb,
    __bf16* __restrict__ Vt)
{
    const int i = blockIdx.x * 256 + threadIdx.x;
    if (i < BATCH * DM) {
        const int b = i >> 10, d = i & (DM - 1);
        Kb[((size_t)b * NKV1 + NKVS) * DM + d] = (__bf16)null_k[d];
    }
    if (i < BATCH * NH * DHD * 8) {  // 16384
        const int bhd = i >> 3, kvp = i & 7;
        Vt[(size_t)bhd * 2056 + 2048 + kvp] = (__bf16)0.0f;
    }
}

// ---------------------------------------------------------------------------
// 256x256-tile GEMM core, m201-faithful 8-phase schedule, BK=64:
// 512 threads (8 waves, 2Mx4N), per-wave 128x64 output.  K as 16 tiles of 64
// in a 2-slot LDS dbuf ([2][256][64] per matrix, 128 KiB total).
// Per K-tile: {pre-gate stage A-lo(t+1); vmcnt(2); barrier} then 4 phases,
// phase q = one C-quadrant (m-frags 2q,2q+1):
//   {ds_read af (4; +bfr 8 in q0); stage 1 half-tile of t+1;
//    [lgkmcnt(8) in q0]; s_barrier; lgkmcnt(0); setprio1; 16 MFMA; setprio0;
//    s_barrier}
// vmcnt never drains below 2 in the main loop (counted, T3+T4).
// Swizzle (st_16x32 equivalent for 128B rows): k-chunk16 ^= (row>>2)&1,
// applied on the pre-swizzled global source and on every ds_read.
// ---------------------------------------------------------------------------
__device__ __forceinline__ void g256_loop(
    const __bf16* __restrict__ A, const __bf16* __restrict__ Bt,
    int Kst, int kbeg, int nt, int m0, int n0,
    __bf16* sa, __bf16* sb, floatx4 (&acc)[8][4])
{
    const int tid = threadIdx.x, lane = tid & 63;
    const int g = lane >> 4, c = lane & 15;
    const int wave = tid >> 6;
    const int wm = wave >> 2, wn = wave & 3;

    // staging: each gld_lds issue covers 64 rows x 64 k (8 KB).
    // thread: row_off = tid>>3 (0..63), dest chunk j = tid&7; source chunk
    // pre-swizzled: j ^ ((row>>2)&1)<<1  with (row>>2)&1 == (tid>>5)&1.
    const int srow = tid >> 3;
    const int jsrc = ((tid & 7) ^ (((tid >> 5) & 1) << 1)) * 8;
    const __bf16* Ag = A  + (size_t)(m0 + srow) * Kst + kbeg + jsrc;
    const __bf16* Bg = Bt + (size_t)(n0 + srow) * Kst + kbeg + jsrc;
    __bf16* la = sa + tid * 8;     // dest base (byte tid*16), linear
    __bf16* lb = sb + tid * 8;

    // stage half hf (rows hf*128..+127) of k-tile kt into dbuf d
#define STG_A(d, hf, kt) do {                                                   \
    gld_lds16(Ag + (size_t)((hf) * 128) * Kst + (kt) * 64,                      \
              la + (d) * 16384 + (hf) * 8192);                                  \
    gld_lds16(Ag + (size_t)((hf) * 128 + 64) * Kst + (kt) * 64,                 \
              la + (d) * 16384 + (hf) * 8192 + 4096);                           \
} while (0)
#define STG_B(d, hf, kt) do {                                                   \
    gld_lds16(Bg + (size_t)((hf) * 128) * Kst + (kt) * 64,                      \
              lb + (d) * 16384 + (hf) * 8192);                                  \
    gld_lds16(Bg + (size_t)((hf) * 128 + 64) * Kst + (kt) * 64,                 \
              lb + (d) * 16384 + (hf) * 8192 + 4096);                           \
} while (0)

    // prologue: all 4 halves of tile 0 (8 loads)
    STG_A(0, 0, 0); STG_A(0, 1, 0); STG_B(0, 0, 0); STG_B(0, 1, 0);

    // read-side: row flip depends only on c: flip2 = ((c>>2)&1)<<1 (chunk XOR)
    const int flip2 = ((c >> 2) & 1) << 1;
    const __bf16* ra = sa + (wm * 128 + c) * 64;   // + d*16384 + (q*32+u*16)*64
    const __bf16* rb = sb + (wn * 64 + c) * 64;    // + d*16384 + (n*16)*64

    for (int t = 0; t < nt; t++) {
        const int d = t & 1, dn = d ^ 1;
        const bool more = (t + 1 < nt);
        if (more) STG_A(dn, 0, t + 1);            // pre-gate stage (2 loads)
        if (more) asm volatile("s_waitcnt vmcnt(2)" ::: "memory");
        else      asm volatile("s_waitcnt vmcnt(0)" ::: "memory");
        __builtin_amdgcn_sched_barrier(0);
        __builtin_amdgcn_s_barrier();             // tile t fully visible
        asm volatile("" ::: "memory");

        const __bf16* rad = ra + d * 16384;
        const __bf16* rbd = rb + d * 16384;
        bf16x8 bfr[4][2];

#pragma unroll
        for (int q = 0; q < 4; q++) {
            // ---- ds-loads for this phase
            if (q == 0) {
#pragma unroll
                for (int n = 0; n < 4; n++)
#pragma unroll
                    for (int kk = 0; kk < 2; kk++)
                        bfr[n][kk] = *(const bf16x8*)(
                            rbd + n * 1024 + (((kk * 4 + g) ^ flip2) * 8));
            }
            bf16x8 af[2][2];
#pragma unroll
            for (int u = 0; u < 2; u++)
#pragma unroll
                for (int kk = 0; kk < 2; kk++)
                    af[u][kk] = *(const bf16x8*)(
                        rad + (q * 32 + u * 16) * 64 + (((kk * 4 + g) ^ flip2) * 8));
            // ---- stage one half-tile of t+1
            if (more) {
                if (q == 0)      STG_A(dn, 1, t + 1);
                else if (q == 1) STG_B(dn, 0, t + 1);
                else if (q == 2) STG_B(dn, 1, t + 1);
            }
            if (q == 0) asm volatile("s_waitcnt lgkmcnt(8)" ::: "memory");
            __builtin_amdgcn_sched_barrier(0);
            __builtin_amdgcn_s_barrier();
            asm volatile("s_waitcnt lgkmcnt(0)" ::: "memory");
            __builtin_amdgcn_sched_barrier(0);
            __builtin_amdgcn_s_setprio(1);
#pragma unroll
            for (int kk = 0; kk < 2; kk++)
#pragma unroll
                for (int u = 0; u < 2; u++)
#pragma unroll
                    for (int n = 0; n < 4; n++)
                        acc[2 * q + u][n] = __builtin_amdgcn_mfma_f32_16x16x32_bf16(
                            af[u][kk], bfr[n][kk], acc[2 * q + u][n], 0, 0, 0);
            __builtin_amdgcn_s_setprio(0);
            __builtin_amdgcn_sched_barrier(0);
            __builtin_amdgcn_s_barrier();
            asm volatile("" ::: "memory");
        }
    }
#undef STG_A
#undef STG_B
}

// XCD-bijective block swizzle: ntot = NX*NY blocks (ntot % 8 == 0); each XCD
// gets a contiguous chunk of logical tiles for L2 reuse.
template<int NX>
__device__ __forceinline__ void g256_decode(int bid, int ntot, int& m0, int& n0)
{
    const int cpx = ntot >> 3;
    const int l = (bid & 7) * cpx + (bid >> 3);
    m0 = (l / NX) * 256;
    n0 = (l % NX) * 256;
}

// MODE 0: bf16 flat [M][N] (+bias, optional GELU).  MODE 4: split-K f32
// partials at [z][M][N] (blockIdx.z = K-slice of 1024).
template<int MODE, int ACT, int NX>
__global__ __launch_bounds__(512, 1) void g256(
    const __bf16* __restrict__ A, const __bf16* __restrict__ Bt,
    const float* __restrict__ bias, void* __restrict__ outp,
    int M, int N, int Kst)
{
    __shared__ __bf16 SA[2][256][64];
    __shared__ __bf16 SB[2][256][64];
    int m0, n0;
    g256_decode<NX>(blockIdx.x, NX * (M >> 8), m0, n0);
    const int kbeg = (MODE == 4) ? (blockIdx.z << 10) : 0;

    floatx4 acc[8][4] = {};
    g256_loop(A, Bt, Kst, kbeg, 16, m0, n0, &SA[0][0][0], &SB[0][0][0], acc);

    const int tid = threadIdx.x, lane = tid & 63, wave = tid >> 6;
    const int g = lane >> 4, c = lane & 15;
    const int wm = wave >> 2, wn = wave & 3;

    __bf16* obf = (__bf16*)outp;
    float*  of  = (float*)outp;
#pragma unroll
    for (int i = 0; i < 8; i++) {
#pragma unroll
        for (int jj = 0; jj < 4; jj++) {
            const int row = m0 + wm * 128 + i * 16 + g * 4;
            const int col = n0 + wn * 64 + jj * 16 + c;
            const float bb = (MODE == 4) ? 0.0f : bias[col];
            float xs[4];
#pragma unroll
            for (int rr = 0; rr < 4; rr++) {
                float x = acc[i][jj][rr] + bb;
                if (ACT == 1) x = gelu_fast(x);
                xs[rr] = x;
            }
            if (MODE == 0) {
#pragma unroll
                for (int rr = 0; rr < 4; rr++)
                    obf[(size_t)(row + rr) * N + col] = (__bf16)xs[rr];
            } else if (MODE == 4) {
#pragma unroll
                for (int rr = 0; rr < 4; rr++)
                    of[((size_t)blockIdx.z * M + row + rr) * N + col] = xs[rr];
            }
        }
    }
}

// Fused Q/K/V projection on the 256-tile core.  grid (64,1,3).
__global__ __launch_bounds__(512, 1) void g256qkv(
    const __bf16* __restrict__ Xn, const __bf16* __restrict__ Yn,
    const __bf16* __restrict__ WqT, const __bf16* __restrict__ WkT,
    const __bf16* __restrict__ WvT,
    const float* __restrict__ bq, const float* __restrict__ bk,
    const float* __restrict__ bv,
    __bf16* __restrict__ Qbf, __bf16* __restrict__ Kbf,
    __bf16* __restrict__ Vt)
{
    __shared__ __bf16 SA[2][256][64];
    __shared__ __bf16 SB[2][256][64];
    const int z = blockIdx.z;
    const __bf16* A    = (z == 0) ? Xn  : Yn;
    const __bf16* Bt   = (z == 0) ? WqT : (z == 1) ? WkT : WvT;
    const float*  bias = (z == 0) ? bq  : (z == 1) ? bk  : bv;

    int m0, n0;
    g256_decode<4>(blockIdx.x, 64, m0, n0);

    floatx4 acc[8][4] = {};
    g256_loop(A, Bt, DM, 0, 16, m0, n0, &SA[0][0][0], &SB[0][0][0], acc);

    const int tid = threadIdx.x, lane = tid & 63, wave = tid >> 6;
    const int g = lane >> 4, c = lane & 15;
    const int wm = wave >> 2, wn = wave & 3;

#pragma unroll
    for (int i = 0; i < 8; i++) {
#pragma unroll
        for (int jj = 0; jj < 4; jj++) {
            const int row = m0 + wm * 128 + i * 16 + g * 4;
            const int col = n0 + wn * 64 + jj * 16 + c;
            const float bb = bias[col];
            float xs[4];
#pragma unroll
            for (int rr = 0; rr < 4; rr++) xs[rr] = acc[i][jj][rr] + bb;
            if (z == 0) {
#pragma unroll
                for (int rr = 0; rr < 4; rr++)
                    Qbf[(size_t)(row + rr) * DM + col] = (__bf16)xs[rr];
            } else if (z == 1) {
#pragma unroll
                for (int rr = 0; rr < 4; rr++) {
                    const int r2 = row + rr;
                    Kbf[(size_t)(r2 + (r2 >> 11)) * DM + col] = (__bf16)xs[rr];
                }
            } else {
                const int b  = row >> 11;
                const int kv = row & 2047;
                const size_t base =
                    ((size_t)((b * NH + (col >> 6)) * DHD + (col & 63))) * 2056 + kv;
                bf16x4 pk;
                pk[0] = (__bf16)xs[0]; pk[1] = (__bf16)xs[1];
                pk[2] = (__bf16)xs[2]; pk[3] = (__bf16)xs[3];
                *(bf16x4*)(Vt + base) = pk;
            }
        }
    }
}

// ---------------------------------------------------------------------------
// FF2 split-K reduction: out = sum_z partials[z] + bias + Hres.  float4/thread.
// ---------------------------------------------------------------------------
__global__ __launch_bounds__(256) void ff2_reduce(
    const float* __restrict__ part, const float* __restrict__ bias,
    const float* __restrict__ Hres, float* __restrict__ out)
{
    const size_t f4 = (size_t)blockIdx.x * 256 + threadIdx.x;  // float4 index
    const int c4 = (int)(f4 & (DM / 4 - 1));
    const size_t stride4 = (size_t)ROWS * DM / 4;
    float4 a = ((const float4*)part)[f4];
    const float4 p1 = ((const float4*)part)[f4 + stride4];
    const float4 p2 = ((const float4*)part)[f4 + 2 * stride4];
    const float4 p3 = ((const float4*)part)[f4 + 3 * stride4];
    const float4 b  = ((const float4*)bias)[c4];
    const float4 hr = ((const float4*)Hres)[f4];
    a.x += p1.x + p2.x + p3.x + b.x + hr.x;
    a.y += p1.y + p2.y + p3.y + b.y + hr.y;
    a.z += p1.z + p2.z + p3.z + b.z + hr.z;
    a.w += p1.w + p2.w + p3.w + b.w + hr.w;
    ((float4*)out)[f4] = a;
}

// ---------------------------------------------------------------------------
// Flash attention (round-8 proven): 128 q/block, 32 q/wave; gld_lds
// XOR-swizzled staging; 4-slot ring, 2 tiles per barrier; v_perm pack;
// ones-MFMA denominator; XCD-local heads.
// ---------------------------------------------------------------------------
__global__ __launch_bounds__(256, 2) void attn_kernel(
    const __bf16* __restrict__ Q, const __bf16* __restrict__ Kb,
    const __bf16* __restrict__ Vt, __bf16* __restrict__ O)
{
    __shared__ __bf16 Ks[4][64][64];   // [kv][d]   32 KB
    __shared__ __bf16 Vs[4][64][64];   // [d][kv]   32 KB

    const int tid = threadIdx.x, lane = tid & 63, w = tid >> 6;
    const int g = lane >> 4, c = lane & 15;

    const int hw   = blockIdx.x;
    const int slot = hw >> 3;
    const int hb   = (hw & 7) | ((slot >> 4) << 3);   // 0..31
    const int h = hb & 15, b = hb >> 4;
    const int q0w = (slot & 15) * 128 + w * 32;

    const float QSC = 0.03125f * 1.44269504088896f;
    bf16x8 qf[2][2];
#pragma unroll
    for (int qt = 0; qt < 2; qt++) {
        const __bf16* Qbase = Q + ((size_t)(b * NQS + q0w + qt * 16 + c)) * DM + h * DHD;
        qf[qt][0] = *(const bf16x8*)(Qbase + g * 8);
        qf[qt][1] = *(const bf16x8*)(Qbase + 32 + g * 8);
#pragma unroll
        for (int e = 0; e < 8; e++) {
            qf[qt][0][e] = (__bf16)((float)qf[qt][0][e] * QSC);
            qf[qt][1][e] = (__bf16)((float)qf[qt][1][e] * QSC);
        }
    }

    // ones fragment for the denominator MFMA (bf16 1.0 = 0x3F80)
    shortx4 ones;
    ones[0] = ones[1] = ones[2] = ones[3] = (short)0x3F80;

    floatx4 dacc[2] = {};        // denominator accumulators (rows identical)
    floatx4 oacc[2][4] = {};

    const int srow = tid >> 3;                    // LDS row 0..31 (and +32)
    const int schk = (tid & 7) ^ (srow & 7);      // swizzled 16B source chunk
    const __bf16* Kg  = Kb + (size_t)b * NKV1 * DM + h * DHD + schk * 8;
    const __bf16* Vg  = Vt + ((size_t)(b * NH + h) * DHD + srow) * 2056;
    const __bf16* Vg2 = Vg + (size_t)32 * 2056;
    const int vcol0 = schk * 8;

    auto stage = [&](int p, int kv0, bool tail) {
        __bf16* kd0 = &Ks[p][0][0]  + tid * 8;
        __bf16* kd1 = &Ks[p][32][0] + tid * 8;
        __bf16* vd0 = &Vs[p][0][0]  + tid * 8;
        __bf16* vd1 = &Vs[p][32][0] + tid * 8;
        if (!tail) {
            gld_lds16(Kg + (size_t)(kv0 + srow) * DM, kd0);
            gld_lds16(Kg + (size_t)(kv0 + srow + 32) * DM, kd1);
            gld_lds16(Vg + kv0 + vcol0, vd0);
            gld_lds16(Vg2 + kv0 + vcol0, vd1);
        } else {
            const int r0 = min(kv0 + srow, NKVS);
            const int r1 = min(kv0 + srow + 32, NKVS);
            const int vc = min(kv0 + vcol0, NKVS);
            gld_lds16(Kg + (size_t)r0 * DM, kd0);
            gld_lds16(Kg + (size_t)r1 * DM, kd1);
            gld_lds16(Vg + vc, vd0);
            gld_lds16(Vg2 + vc, vd1);
        }
    };

    auto compute = [&](int p, int kv0, bool tail) {
        floatx4 s[2][4];
#pragma unroll
        for (int qt = 0; qt < 2; qt++)
#pragma unroll
            for (int kvt = 0; kvt < 4; kvt++)
#pragma unroll
                for (int r = 0; r < 4; r++) s[qt][kvt][r] = -6.0f;

        const int sw = c & 7;
        __builtin_amdgcn_s_setprio(1);
#pragma unroll
        for (int kvt = 0; kvt < 4; kvt++) {
            const bf16x8 kf0 = *(const bf16x8*)&Ks[p][kvt * 16 + c][(g ^ sw) * 8];
            const bf16x8 kf1 = *(const bf16x8*)&Ks[p][kvt * 16 + c][((4 | g) ^ sw) * 8];
#pragma unroll
            for (int qt = 0; qt < 2; qt++) {
                s[qt][kvt] = __builtin_amdgcn_mfma_f32_16x16x32_bf16(kf0, qf[qt][0], s[qt][kvt], 0, 0, 0);
                s[qt][kvt] = __builtin_amdgcn_mfma_f32_16x16x32_bf16(kf1, qf[qt][1], s[qt][kvt], 0, 0, 0);
            }
        }
        __builtin_amdgcn_s_setprio(0);

        if (tail) {
#pragma unroll
            for (int qt = 0; qt < 2; qt++)
#pragma unroll
                for (int kvt = 0; kvt < 4; kvt++)
#pragma unroll
                    for (int r = 0; r < 4; r++)
                        if (kv0 + kvt * 16 + g * 4 + r >= NKV1) s[qt][kvt][r] = -1e30f;
        }

        // p = exp2(s); pack to bf16 by truncation via v_perm (1 op per word)
        shortx4 pf[2][4];
#pragma unroll
        for (int qt = 0; qt < 2; qt++)
#pragma unroll
            for (int kvt = 0; kvt < 4; kvt++) {
                const unsigned u0 = __builtin_bit_cast(unsigned, __builtin_amdgcn_exp2f(s[qt][kvt][0]));
                const unsigned u1 = __builtin_bit_cast(unsigned, __builtin_amdgcn_exp2f(s[qt][kvt][1]));
                const unsigned u2 = __builtin_bit_cast(unsigned, __builtin_amdgcn_exp2f(s[qt][kvt][2]));
                const unsigned u3 = __builtin_bit_cast(unsigned, __builtin_amdgcn_exp2f(s[qt][kvt][3]));
                unsigned pk0 = __builtin_amdgcn_perm(u1, u0, 0x07060302u);
                unsigned pk1 = __builtin_amdgcn_perm(u3, u2, 0x07060302u);
                unsigned long long pk = ((unsigned long long)pk1 << 32) | pk0;
                pf[qt][kvt] = __builtin_bit_cast(shortx4, pk);
            }

        // O^T += V^T P^T ; denominator via ones-row MFMA
        __builtin_amdgcn_s_setprio(1);
#pragma unroll
        for (int kvt = 0; kvt < 4; kvt++) {
            shortx4 vfr[4];
#pragma unroll
            for (int dt = 0; dt < 4; dt++) {
                const int slotp = (kvt * 2 + (g >> 1)) ^ sw;
                vfr[dt] = *(const shortx4*)&Vs[p][dt * 16 + c][slotp * 8 + (g & 1) * 4];
            }
#pragma unroll
            for (int dt = 0; dt < 4; dt++)
#pragma unroll
                for (int qt = 0; qt < 2; qt++)
                    oacc[qt][dt] = __builtin_amdgcn_mfma_f32_16x16x16bf16_1k(
                        vfr[dt], pf[qt][kvt], oacc[qt][dt], 0, 0, 0);
#pragma unroll
            for (int qt = 0; qt < 2; qt++)
                dacc[qt] = __builtin_amdgcn_mfma_f32_16x16x16bf16_1k(
                    ones, pf[qt][kvt], dacc[qt], 0, 0, 0);
        }
        __builtin_amdgcn_s_setprio(0);
    };

    // 4-slot ring, 2 tiles per barrier period.  Tiles 0..32 (32 = tail).
    stage(0, 0, false);
    stage(1, 64, false);
    __syncthreads();
    for (int it = 0; it < 32; it += 2) {
        stage((it + 2) & 3, (it + 2) * 64, (it + 2) == 32);
        if (it + 3 <= 32) stage((it + 3) & 3, (it + 3) * 64, false);
        compute(it & 3, it * 64, false);
        compute((it + 1) & 3, (it + 1) * 64, false);
        __syncthreads();                 // staged tiles visible; reads done
    }
    compute(0, 2048, true);              // tail tile (32) in slot 0

#pragma unroll
    for (int qt = 0; qt < 2; qt++) {
        const float inv_l = 1.0f / dacc[qt][0];
        __bf16* Ob = O + ((size_t)(b * NQS + q0w + qt * 16 + c)) * DM + h * DHD;
#pragma unroll
        for (int dt = 0; dt < 4; dt++) {
            bf16x4 ob;
#pragma unroll
            for (int r = 0; r < 4; r++) ob[r] = (__bf16)(oacc[qt][dt][r] * inv_l);
            *(bf16x4*)(Ob + dt * 16 + g * 4) = ob;
        }
    }
}

// ---------------------------------------------------------------------------
extern "C" void kernel_launch(void* const* d_in, const int* in_sizes, int n_in,
                              void* d_out, int out_size, void* d_ws, size_t ws_size,
                              hipStream_t stream)
{
    const float* X      = (const float*)d_in[0];
    const float* Y      = (const float*)d_in[1];
    const float* Wq     = (const float*)d_in[2];
    const float* bq     = (const float*)d_in[3];
    const float* Wk     = (const float*)d_in[4];
    const float* bk     = (const float*)d_in[5];
    const float* Wv     = (const float*)d_in[6];
    const float* bv     = (const float*)d_in[7];
    const float* null_k = (const float*)d_in[8];
    const float* g0     = (const float*)d_in[9];
    const float* b0     = (const float*)d_in[10];
    const float* g0kv   = (const float*)d_in[11];
    const float* b0kv   = (const float*)d_in[12];
    const float* g1     = (const float*)d_in[13];
    const float* b1     = (const float*)d_in[14];
    const float* W1     = (const float*)d_in[15];
    const float* bf1    = (const float*)d_in[16];
    const float* W2     = (const float*)d_in[17];
    const float* bf2    = (const float*)d_in[18];
    float* out = (float*)d_out;

    // workspace carve (bytes).  Persistent-through-FF2 buffers FIRST so the
    // tail region (dead by FF2 time) can be reused for split-K partials.
    char* p = (char*)d_ws;
    __bf16* W2T  = (__bf16*)p; p += (size_t)4 * DM * DM * 2;          // [1024][4096]
    float*  Hres = (float*)p;  p += (size_t)ROWS * DM * 4;
    __bf16* Gbf  = (__bf16*)p; p += (size_t)ROWS * 4 * DM * 2;
    char* scratch = p;                                                // dead by FF2
    __bf16* Xn   = (__bf16*)p; p += (size_t)ROWS * DM * 2;
    __bf16* Yn   = (__bf16*)p; p += (size_t)ROWS * DM * 2;
    __bf16* WqT  = (__bf16*)p; p += (size_t)DM * DM * 2;
    __bf16* WkT  = (__bf16*)p; p += (size_t)DM * DM * 2;
    __bf16* WvT  = (__bf16*)p; p += (size_t)DM * DM * 2;
    __bf16* W1T  = (__bf16*)p; p += (size_t)4 * DM * DM * 2;          // [4096][1024]
    __bf16* Qbf  = (__bf16*)p; p += (size_t)ROWS * DM * 2;
    __bf16* Kbf  = (__bf16*)p; p += (size_t)BATCH * NKV1 * DM * 2;
    __bf16* Vt   = (__bf16*)p; p += (size_t)BATCH * NH * DHD * 2056 * 2;
    __bf16* Obf  = (__bf16*)p; p += (size_t)ROWS * DM * 2;
    __bf16* Hr   = (__bf16*)p; p += (size_t)ROWS * DM * 2;
    float* Part  = (float*)scratch;  // FF2 partials: 4 x ROWS x DM f32 = 67 MB

    // 1. LayerNorms (fused X+Y, one launch)
    ln2_to_bf16<<<2 * ROWS, 256, 0, stream>>>(X, Y, g0, b0, g0kv, b0kv, Xn, Yn);

    // 2. weight transposes (f32 -> bf16, W^T), two launches total
    transpose3_f32_bf16<<<dim3(DM / 32, DM / 32, 3), dim3(32, 8), 0, stream>>>(
        Wq, Wk, Wv, WqT, WkT, WvT);
    transpose_ffw<<<dim3(128, 32, 2), dim3(32, 8), 0, stream>>>(W1, W2, W1T, W2T);

    // 3. fused Q/K/V projections on the 8-phase BK=64 256-tile core
    g256qkv<<<dim3(64, 1, 3), 512, 0, stream>>>(
        Xn, Yn, WqT, WkT, WvT, bq, bk, bv, Qbf, Kbf, Vt);
    fill_null<<<64, 256, 0, stream>>>(null_k, Kbf, Vt);

    // 4. attention (4-slot ring, 2 tiles/barrier, XCD-local heads)
    attn_kernel<<<dim3(512), 256, 0, stream>>>(Qbf, Kbf, Vt, Obf);

    // 5. residual + LN
    resid_ln<<<ROWS, 256, 0, stream>>>(X, Obf, g1, b1, Hres, Hr);

    // 6. FFN: FF1 (bf16 + GELU), FF2 split-K=4 partials, then reduce
    g256<0, 1, 16><<<dim3(256), 512, 0, stream>>>(
        Hr, W1T, bf1, (void*)Gbf, ROWS, 4 * DM, DM);
    g256<4, 0, 4><<<dim3(64, 1, 4), 512, 0, stream>>>(
        Gbf, W2T, bf2, (void*)Part, ROWS, DM, 4 * DM);
    ff2_reduce<<<ROWS * DM / 1024, 256, 0, stream>>>(Part, bf2, Hres, out);
}

// Round 11
// 335.780 us; speedup vs baseline: 1.0530x; 1.0233x over previous
//
#include <hip/hip_runtime.h>
#include <hip/hip_bf16.h>
#include <math.h>
#include <stdint.h>

typedef __bf16 bf16x8 __attribute__((ext_vector_type(8)));
typedef __bf16 bf16x4 __attribute__((ext_vector_type(4)));
typedef float floatx4 __attribute__((ext_vector_type(4)));
typedef short shortx4 __attribute__((ext_vector_type(4)));
typedef unsigned int uintx4 __attribute__((ext_vector_type(4)));

#define NQS   2048
#define NKVS  2048
#define NKV1  2049
#define DM    1024
#define NH    16
#define DHD   64
#define BATCH 2
#define ROWS  (BATCH * NQS)   // 4096

// async global->LDS, 16B per lane. LDS dest must be wave-uniform base + lane*16.
__device__ __forceinline__ void gld_lds16(const __bf16* gp, __bf16* lp) {
    __builtin_amdgcn_global_load_lds(
        (const __attribute__((address_space(1))) uint32_t*)(uintptr_t)gp,
        (__attribute__((address_space(3))) uint32_t*)(uintptr_t)lp,
        16, 0, 0);
}

// tanh-form GELU in exp2 domain
__device__ __forceinline__ float gelu_fast(float x) {
    const float u = x * x;
    const float e = __builtin_amdgcn_exp2f(x * (-2.3022077f + (-0.1029431f) * u));
    return x * __builtin_amdgcn_rcpf(1.0f + e);
}

// ---------------------------------------------------------------------------
// Fused LayerNorm for X and Y (f32 in) -> bf16 out.  grid 2*ROWS.
// ---------------------------------------------------------------------------
__global__ __launch_bounds__(256) void ln2_to_bf16(
    const float* __restrict__ X, const float* __restrict__ Y,
    const float* __restrict__ g0, const float* __restrict__ b0,
    const float* __restrict__ g0kv, const float* __restrict__ b0kv,
    __bf16* __restrict__ Xn, __bf16* __restrict__ Yn)
{
    int row = blockIdx.x;
    const float *src, *gamma, *beta; __bf16* dst;
    if (row < ROWS) { src = X; gamma = g0; beta = b0; dst = Xn; }
    else { row -= ROWS; src = Y; gamma = g0kv; beta = b0kv; dst = Yn; }
    const int tid = threadIdx.x;
    const float4 v = ((const float4*)(src + (size_t)row * DM))[tid];
    float s  = v.x + v.y + v.z + v.w;
    float sq = v.x * v.x + v.y * v.y + v.z * v.z + v.w * v.w;
    for (int off = 1; off < 64; off <<= 1) {
        s  += __shfl_xor(s, off);
        sq += __shfl_xor(sq, off);
    }
    __shared__ float red[8];
    const int wave = tid >> 6, lane = tid & 63;
    if (lane == 0) { red[wave * 2] = s; red[wave * 2 + 1] = sq; }
    __syncthreads();
    s  = red[0] + red[2] + red[4] + red[6];
    sq = red[1] + red[3] + red[5] + red[7];
    const float mu  = s * (1.0f / DM);
    const float var = sq * (1.0f / DM) - mu * mu;
    const float rs  = rsqrtf(var + 1e-5f);
    const float4 gv = ((const float4*)gamma)[tid];
    const float4 bv = ((const float4*)beta)[tid];
    bf16x4 o;
    o[0] = (__bf16)((v.x - mu) * rs * gv.x + bv.x);
    o[1] = (__bf16)((v.y - mu) * rs * gv.y + bv.y);
    o[2] = (__bf16)((v.z - mu) * rs * gv.z + bv.z);
    o[3] = (__bf16)((v.w - mu) * rs * gv.w + bv.w);
    *(bf16x4*)(dst + (size_t)row * DM + tid * 4) = o;
}

// ---------------------------------------------------------------------------
// Residual add + LayerNorm: Hres = X + O (f32 out), Hr = LN(Hres) (bf16 out)
// ---------------------------------------------------------------------------
__global__ __launch_bounds__(256) void resid_ln(
    const float* __restrict__ X, const __bf16* __restrict__ O,
    const float* __restrict__ gamma, const float* __restrict__ beta,
    float* __restrict__ Hres, __bf16* __restrict__ Hr)
{
    const int row = blockIdx.x;
    const int tid = threadIdx.x;
    const float4 xv = ((const float4*)(X + (size_t)row * DM))[tid];
    const bf16x4 ov = *(const bf16x4*)(O + (size_t)row * DM + tid * 4);
    float4 v;
    v.x = xv.x + (float)ov[0];
    v.y = xv.y + (float)ov[1];
    v.z = xv.z + (float)ov[2];
    v.w = xv.w + (float)ov[3];
    ((float4*)(Hres + (size_t)row * DM))[tid] = v;

    float s  = v.x + v.y + v.z + v.w;
    float sq = v.x * v.x + v.y * v.y + v.z * v.z + v.w * v.w;
    for (int off = 1; off < 64; off <<= 1) {
        s  += __shfl_xor(s, off);
        sq += __shfl_xor(sq, off);
    }
    __shared__ float red[8];
    const int wave = tid >> 6, lane = tid & 63;
    if (lane == 0) { red[wave * 2] = s; red[wave * 2 + 1] = sq; }
    __syncthreads();
    s  = red[0] + red[2] + red[4] + red[6];
    sq = red[1] + red[3] + red[5] + red[7];
    const float mu  = s * (1.0f / DM);
    const float var = sq * (1.0f / DM) - mu * mu;
    const float rs  = rsqrtf(var + 1e-5f);
    const float4 gv = ((const float4*)gamma)[tid];
    const float4 bv = ((const float4*)beta)[tid];
    bf16x4 o;
    o[0] = (__bf16)((v.x - mu) * rs * gv.x + bv.x);
    o[1] = (__bf16)((v.y - mu) * rs * gv.y + bv.y);
    o[2] = (__bf16)((v.z - mu) * rs * gv.z + bv.z);
    o[3] = (__bf16)((v.w - mu) * rs * gv.w + bv.w);
    *(bf16x4*)(Hr + (size_t)row * DM + tid * 4) = o;
}

// Fused transpose of the three 1024x1024 QKV weights (one launch, z picks W).
__global__ __launch_bounds__(256) void transpose3_f32_bf16(
    const float* __restrict__ Wq, const float* __restrict__ Wk,
    const float* __restrict__ Wv, __bf16* __restrict__ WqT,
    __bf16* __restrict__ WkT, __bf16* __restrict__ WvT)
{
    __shared__ float tile[32][33];
    const int z = blockIdx.z;
    const float* in = (z == 0) ? Wq : (z == 1) ? Wk : Wv;
    __bf16* out = (z == 0) ? WqT : (z == 1) ? WkT : WvT;
    const int c0 = blockIdx.x * 32, r0 = blockIdx.y * 32;
    const int tx = threadIdx.x, ty = threadIdx.y;
#pragma unroll
    for (int i = 0; i < 4; i++)
        tile[ty + i * 8][tx] = in[(size_t)(r0 + ty + i * 8) * DM + c0 + tx];
    __syncthreads();
#pragma unroll
    for (int i = 0; i < 4; i++)
        out[(size_t)(c0 + ty + i * 8) * DM + r0 + tx] = (__bf16)tile[tx][ty + i * 8];
}

// Fused transpose of W1 [1024][4096] and W2 [4096][1024] (z picks).
__global__ __launch_bounds__(256) void transpose_ffw(
    const float* __restrict__ W1, const float* __restrict__ W2,
    __bf16* __restrict__ W1T, __bf16* __restrict__ W2T)
{
    __shared__ float tile[32][33];
    const int z = blockIdx.z;
    const float* in; __bf16* out; int R, C, c0, r0;
    if (z == 0) { in = W1; out = W1T; R = DM; C = 4 * DM; c0 = blockIdx.x * 32; r0 = blockIdx.y * 32; }
    else        { in = W2; out = W2T; R = 4 * DM; C = DM; c0 = blockIdx.y * 32; r0 = blockIdx.x * 32; }
    const int tx = threadIdx.x, ty = threadIdx.y;
#pragma unroll
    for (int i = 0; i < 4; i++)
        tile[ty + i * 8][tx] = in[(size_t)(r0 + ty + i * 8) * C + c0 + tx];
    __syncthreads();
#pragma unroll
    for (int i = 0; i < 4; i++)
        out[(size_t)(c0 + ty + i * 8) * R + r0 + tx] = (__bf16)tile[tx][ty + i * 8];
}

// ---------------------------------------------------------------------------
// Fill null-K row (kv==2048) with null_k, and zero Vt pad columns [2048,2056)
// ---------------------------------------------------------------------------
__global__ __launch_bounds__(256) void fill_null(
    const float* __restrict__ null_k, __bf16* __restrict__ Kb,
    __bf16* __restrict__ Vt)
{
    const int i = blockIdx.x * 256 + threadIdx.x;
    if (i < BATCH * DM) {
        const int b = i >> 10, d = i & (DM - 1);
        Kb[((size_t)b * NKV1 + NKVS) * DM + d] = (__bf16)null_k[d];
    }
    if (i < BATCH * NH * DHD * 8) {  // 16384
        const int bhd = i >> 3, kvp = i & 7;
        Vt[(size_t)bhd * 2056 + 2048 + kvp] = (__bf16)0.0f;
    }
}

// ---------------------------------------------------------------------------
// 256x256-tile GEMM core, m201-faithful 8-phase schedule, BK=64 (round-10).
// ---------------------------------------------------------------------------
__device__ __forceinline__ void g256_loop(
    const __bf16* __restrict__ A, const __bf16* __restrict__ Bt,
    int Kst, int kbeg, int nt, int m0, int n0,
    __bf16* sa, __bf16* sb, floatx4 (&acc)[8][4])
{
    const int tid = threadIdx.x, lane = tid & 63;
    const int g = lane >> 4, c = lane & 15;
    const int wave = tid >> 6;
    const int wm = wave >> 2, wn = wave & 3;

    const int srow = tid >> 3;
    const int jsrc = ((tid & 7) ^ (((tid >> 5) & 1) << 1)) * 8;
    const __bf16* Ag = A  + (size_t)(m0 + srow) * Kst + kbeg + jsrc;
    const __bf16* Bg = Bt + (size_t)(n0 + srow) * Kst + kbeg + jsrc;
    __bf16* la = sa + tid * 8;     // dest base (byte tid*16), linear
    __bf16* lb = sb + tid * 8;

#define STG_A(d, hf, kt) do {                                                   \
    gld_lds16(Ag + (size_t)((hf) * 128) * Kst + (kt) * 64,                      \
              la + (d) * 16384 + (hf) * 8192);                                  \
    gld_lds16(Ag + (size_t)((hf) * 128 + 64) * Kst + (kt) * 64,                 \
              la + (d) * 16384 + (hf) * 8192 + 4096);                           \
} while (0)
#define STG_B(d, hf, kt) do {                                                   \
    gld_lds16(Bg + (size_t)((hf) * 128) * Kst + (kt) * 64,                      \
              lb + (d) * 16384 + (hf) * 8192);                                  \
    gld_lds16(Bg + (size_t)((hf) * 128 + 64) * Kst + (kt) * 64,                 \
              lb + (d) * 16384 + (hf) * 8192 + 4096);                           \
} while (0)

    // prologue: all 4 halves of tile 0 (8 loads)
    STG_A(0, 0, 0); STG_A(0, 1, 0); STG_B(0, 0, 0); STG_B(0, 1, 0);

    const int flip2 = ((c >> 2) & 1) << 1;
    const __bf16* ra = sa + (wm * 128 + c) * 64;
    const __bf16* rb = sb + (wn * 64 + c) * 64;

    for (int t = 0; t < nt; t++) {
        const int d = t & 1, dn = d ^ 1;
        const bool more = (t + 1 < nt);
        if (more) STG_A(dn, 0, t + 1);            // pre-gate stage (2 loads)
        if (more) asm volatile("s_waitcnt vmcnt(2)" ::: "memory");
        else      asm volatile("s_waitcnt vmcnt(0)" ::: "memory");
        __builtin_amdgcn_sched_barrier(0);
        __builtin_amdgcn_s_barrier();             // tile t fully visible
        asm volatile("" ::: "memory");

        const __bf16* rad = ra + d * 16384;
        const __bf16* rbd = rb + d * 16384;
        bf16x8 bfr[4][2];

#pragma unroll
        for (int q = 0; q < 4; q++) {
            if (q == 0) {
#pragma unroll
                for (int n = 0; n < 4; n++)
#pragma unroll
                    for (int kk = 0; kk < 2; kk++)
                        bfr[n][kk] = *(const bf16x8*)(
                            rbd + n * 1024 + (((kk * 4 + g) ^ flip2) * 8));
            }
            bf16x8 af[2][2];
#pragma unroll
            for (int u = 0; u < 2; u++)
#pragma unroll
                for (int kk = 0; kk < 2; kk++)
                    af[u][kk] = *(const bf16x8*)(
                        rad + (q * 32 + u * 16) * 64 + (((kk * 4 + g) ^ flip2) * 8));
            if (more) {
                if (q == 0)      STG_A(dn, 1, t + 1);
                else if (q == 1) STG_B(dn, 0, t + 1);
                else if (q == 2) STG_B(dn, 1, t + 1);
            }
            if (q == 0) asm volatile("s_waitcnt lgkmcnt(8)" ::: "memory");
            __builtin_amdgcn_sched_barrier(0);
            __builtin_amdgcn_s_barrier();
            asm volatile("s_waitcnt lgkmcnt(0)" ::: "memory");
            __builtin_amdgcn_sched_barrier(0);
            __builtin_amdgcn_s_setprio(1);
#pragma unroll
            for (int kk = 0; kk < 2; kk++)
#pragma unroll
                for (int u = 0; u < 2; u++)
#pragma unroll
                    for (int n = 0; n < 4; n++)
                        acc[2 * q + u][n] = __builtin_amdgcn_mfma_f32_16x16x32_bf16(
                            af[u][kk], bfr[n][kk], acc[2 * q + u][n], 0, 0, 0);
            __builtin_amdgcn_s_setprio(0);
            __builtin_amdgcn_sched_barrier(0);
            __builtin_amdgcn_s_barrier();
            asm volatile("" ::: "memory");
        }
    }
#undef STG_A
#undef STG_B
}

// XCD-bijective block swizzle: ntot = NX*NY blocks (ntot % 8 == 0); each XCD
// gets a contiguous chunk of logical tiles for L2 reuse.
template<int NX>
__device__ __forceinline__ void g256_decode(int bid, int ntot, int& m0, int& n0)
{
    const int cpx = ntot >> 3;
    const int l = (bid & 7) * cpx + (bid >> 3);
    m0 = (l / NX) * 256;
    n0 = (l % NX) * 256;
}

// MODE 0: bf16 flat [M][N] (+bias, optional GELU).  MODE 4: split-K f32
// partials at [z][M][N] (blockIdx.z = K-slice of 1024).
template<int MODE, int ACT, int NX>
__global__ __launch_bounds__(512, 1) void g256(
    const __bf16* __restrict__ A, const __bf16* __restrict__ Bt,
    const float* __restrict__ bias, void* __restrict__ outp,
    int M, int N, int Kst)
{
    __shared__ __bf16 SA[2][256][64];
    __shared__ __bf16 SB[2][256][64];
    int m0, n0;
    g256_decode<NX>(blockIdx.x, NX * (M >> 8), m0, n0);
    const int kbeg = (MODE == 4) ? (blockIdx.z << 10) : 0;

    floatx4 acc[8][4] = {};
    g256_loop(A, Bt, Kst, kbeg, 16, m0, n0, &SA[0][0][0], &SB[0][0][0], acc);

    const int tid = threadIdx.x, lane = tid & 63, wave = tid >> 6;
    const int g = lane >> 4, c = lane & 15;
    const int wm = wave >> 2, wn = wave & 3;

    __bf16* obf = (__bf16*)outp;
    float*  of  = (float*)outp;
#pragma unroll
    for (int i = 0; i < 8; i++) {
#pragma unroll
        for (int jj = 0; jj < 4; jj++) {
            const int row = m0 + wm * 128 + i * 16 + g * 4;
            const int col = n0 + wn * 64 + jj * 16 + c;
            const float bb = (MODE == 4) ? 0.0f : bias[col];
            float xs[4];
#pragma unroll
            for (int rr = 0; rr < 4; rr++) {
                float x = acc[i][jj][rr] + bb;
                if (ACT == 1) x = gelu_fast(x);
                xs[rr] = x;
            }
            if (MODE == 0) {
#pragma unroll
                for (int rr = 0; rr < 4; rr++)
                    obf[(size_t)(row + rr) * N + col] = (__bf16)xs[rr];
            } else if (MODE == 4) {
#pragma unroll
                for (int rr = 0; rr < 4; rr++)
                    of[((size_t)blockIdx.z * M + row + rr) * N + col] = xs[rr];
            }
        }
    }
}

// Fused Q/K/V projection on the 256-tile core.  grid (64,1,3).
__global__ __launch_bounds__(512, 1) void g256qkv(
    const __bf16* __restrict__ Xn, const __bf16* __restrict__ Yn,
    const __bf16* __restrict__ WqT, const __bf16* __restrict__ WkT,
    const __bf16* __restrict__ WvT,
    const float* __restrict__ bq, const float* __restrict__ bk,
    const float* __restrict__ bv,
    __bf16* __restrict__ Qbf, __bf16* __restrict__ Kbf,
    __bf16* __restrict__ Vt)
{
    __shared__ __bf16 SA[2][256][64];
    __shared__ __bf16 SB[2][256][64];
    const int z = blockIdx.z;
    const __bf16* A    = (z == 0) ? Xn  : Yn;
    const __bf16* Bt   = (z == 0) ? WqT : (z == 1) ? WkT : WvT;
    const float*  bias = (z == 0) ? bq  : (z == 1) ? bk  : bv;

    int m0, n0;
    g256_decode<4>(blockIdx.x, 64, m0, n0);

    floatx4 acc[8][4] = {};
    g256_loop(A, Bt, DM, 0, 16, m0, n0, &SA[0][0][0], &SB[0][0][0], acc);

    const int tid = threadIdx.x, lane = tid & 63, wave = tid >> 6;
    const int g = lane >> 4, c = lane & 15;
    const int wm = wave >> 2, wn = wave & 3;

#pragma unroll
    for (int i = 0; i < 8; i++) {
#pragma unroll
        for (int jj = 0; jj < 4; jj++) {
            const int row = m0 + wm * 128 + i * 16 + g * 4;
            const int col = n0 + wn * 64 + jj * 16 + c;
            const float bb = bias[col];
            float xs[4];
#pragma unroll
            for (int rr = 0; rr < 4; rr++) xs[rr] = acc[i][jj][rr] + bb;
            if (z == 0) {
#pragma unroll
                for (int rr = 0; rr < 4; rr++)
                    Qbf[(size_t)(row + rr) * DM + col] = (__bf16)xs[rr];
            } else if (z == 1) {
#pragma unroll
                for (int rr = 0; rr < 4; rr++) {
                    const int r2 = row + rr;
                    Kbf[(size_t)(r2 + (r2 >> 11)) * DM + col] = (__bf16)xs[rr];
                }
            } else {
                const int b  = row >> 11;
                const int kv = row & 2047;
                const size_t base =
                    ((size_t)((b * NH + (col >> 6)) * DHD + (col & 63))) * 2056 + kv;
                bf16x4 pk;
                pk[0] = (__bf16)xs[0]; pk[1] = (__bf16)xs[1];
                pk[2] = (__bf16)xs[2]; pk[3] = (__bf16)xs[3];
                *(bf16x4*)(Vt + base) = pk;
            }
        }
    }
}

// ---------------------------------------------------------------------------
// FF2 split-K reduction: out = sum_z partials[z] + bias + Hres.  float4/thread.
// ---------------------------------------------------------------------------
__global__ __launch_bounds__(256) void ff2_reduce(
    const float* __restrict__ part, const float* __restrict__ bias,
    const float* __restrict__ Hres, float* __restrict__ out)
{
    const size_t f4 = (size_t)blockIdx.x * 256 + threadIdx.x;  // float4 index
    const int c4 = (int)(f4 & (DM / 4 - 1));
    const size_t stride4 = (size_t)ROWS * DM / 4;
    float4 a = ((const float4*)part)[f4];
    const float4 p1 = ((const float4*)part)[f4 + stride4];
    const float4 p2 = ((const float4*)part)[f4 + 2 * stride4];
    const float4 p3 = ((const float4*)part)[f4 + 3 * stride4];
    const float4 b  = ((const float4*)bias)[c4];
    const float4 hr = ((const float4*)Hres)[f4];
    a.x += p1.x + p2.x + p3.x + b.x + hr.x;
    a.y += p1.y + p2.y + p3.y + b.y + hr.y;
    a.z += p1.z + p2.z + p3.z + b.z + hr.z;
    a.w += p1.w + p2.w + p3.w + b.w + hr.w;
    ((float4*)out)[f4] = a;
}

// ---------------------------------------------------------------------------
// Flash attention v5: PV upgraded to mfma 16x16x32 via PERMUTED K-row
// staging.  Softmax is permutation-invariant over kv, so K rows are loaded
// in the order a(i) = (i>>5)*32 + ((i&15)>>2)*8 + ((i>>4)&1)*4 + (i&3)
// (bijective).  Then lane (g,c)'s packed P-words for subtile pair (2w,2w+1)
// concatenate directly into the K=32 B-operand (kv = w*32 + g*8 + 0..7),
// and V (natural order) supplies the A-operand as one contiguous bf16x8.
// PV+denominator MFMA issue slots halve: 40 -> 20 per tile.
// Everything else (4-slot ring, 2 tiles/barrier, v_perm pack, ones-MFMA
// denominator, XCD-local heads) unchanged from round 8.
// ---------------------------------------------------------------------------
__global__ __launch_bounds__(256, 2) void attn_kernel(
    const __bf16* __restrict__ Q, const __bf16* __restrict__ Kb,
    const __bf16* __restrict__ Vt, __bf16* __restrict__ O)
{
    __shared__ __bf16 Ks[4][64][64];   // [kv][d]   32 KB
    __shared__ __bf16 Vs[4][64][64];   // [d][kv]   32 KB

    const int tid = threadIdx.x, lane = tid & 63, w = tid >> 6;
    const int g = lane >> 4, c = lane & 15;

    const int hw   = blockIdx.x;
    const int slot = hw >> 3;
    const int hb   = (hw & 7) | ((slot >> 4) << 3);   // 0..31
    const int h = hb & 15, b = hb >> 4;
    const int q0w = (slot & 15) * 128 + w * 32;

    const float QSC = 0.03125f * 1.44269504088896f;
    bf16x8 qf[2][2];
#pragma unroll
    for (int qt = 0; qt < 2; qt++) {
        const __bf16* Qbase = Q + ((size_t)(b * NQS + q0w + qt * 16 + c)) * DM + h * DHD;
        qf[qt][0] = *(const bf16x8*)(Qbase + g * 8);
        qf[qt][1] = *(const bf16x8*)(Qbase + 32 + g * 8);
#pragma unroll
        for (int e = 0; e < 8; e++) {
            qf[qt][0][e] = (__bf16)((float)qf[qt][0][e] * QSC);
            qf[qt][1][e] = (__bf16)((float)qf[qt][1][e] * QSC);
        }
    }

    // ones A-fragment for the denominator MFMA (K=32)
    bf16x8 ones8;
#pragma unroll
    for (int e = 0; e < 8; e++) ones8[e] = (__bf16)1.0f;

    floatx4 dacc[2] = {};        // denominator accumulators (rows identical)
    floatx4 oacc[2][4] = {};

    const int srow = tid >> 3;                    // LDS row 0..31 (and +32)
    const int schk = (tid & 7) ^ (srow & 7);      // swizzled 16B source chunk
    // permuted K source row: LDS row i holds actual kv offset a(i)
    const int sr4 = srow & 15, st0 = srow >> 4;
    const int prow = ((sr4 >> 2) << 3) + (st0 << 2) + (sr4 & 3);   // 0..31
    const __bf16* Kg  = Kb + (size_t)b * NKV1 * DM + h * DHD + schk * 8;
    const __bf16* Vg  = Vt + ((size_t)(b * NH + h) * DHD + srow) * 2056;
    const __bf16* Vg2 = Vg + (size_t)32 * 2056;
    const int vcol0 = schk * 8;

    auto stage = [&](int p, int kv0, bool tail) {
        __bf16* kd0 = &Ks[p][0][0]  + tid * 8;
        __bf16* kd1 = &Ks[p][32][0] + tid * 8;
        __bf16* vd0 = &Vs[p][0][0]  + tid * 8;
        __bf16* vd1 = &Vs[p][32][0] + tid * 8;
        if (!tail) {
            gld_lds16(Kg + (size_t)(kv0 + prow) * DM, kd0);
            gld_lds16(Kg + (size_t)(kv0 + prow + 32) * DM, kd1);
            gld_lds16(Vg + kv0 + vcol0, vd0);
            gld_lds16(Vg2 + kv0 + vcol0, vd1);
        } else {
            const int r0 = min(kv0 + prow, NKVS);
            const int r1 = min(kv0 + prow + 32, NKVS);
            const int vc = min(kv0 + vcol0, NKVS);
            gld_lds16(Kg + (size_t)r0 * DM, kd0);
            gld_lds16(Kg + (size_t)r1 * DM, kd1);
            gld_lds16(Vg + vc, vd0);
            gld_lds16(Vg2 + vc, vd1);
        }
    };

    auto compute = [&](int p, int kv0, bool tail) {
        floatx4 s[2][4];
#pragma unroll
        for (int qt = 0; qt < 2; qt++)
#pragma unroll
            for (int kvt = 0; kvt < 4; kvt++)
#pragma unroll
                for (int r = 0; r < 4; r++) s[qt][kvt][r] = -6.0f;

        const int sw = c & 7;
        __builtin_amdgcn_s_setprio(1);
#pragma unroll
        for (int kvt = 0; kvt < 4; kvt++) {
            const bf16x8 kf0 = *(const bf16x8*)&Ks[p][kvt * 16 + c][(g ^ sw) * 8];
            const bf16x8 kf1 = *(const bf16x8*)&Ks[p][kvt * 16 + c][((4 | g) ^ sw) * 8];
#pragma unroll
            for (int qt = 0; qt < 2; qt++) {
                s[qt][kvt] = __builtin_amdgcn_mfma_f32_16x16x32_bf16(kf0, qf[qt][0], s[qt][kvt], 0, 0, 0);
                s[qt][kvt] = __builtin_amdgcn_mfma_f32_16x16x32_bf16(kf1, qf[qt][1], s[qt][kvt], 0, 0, 0);
            }
        }
        __builtin_amdgcn_s_setprio(0);

        if (tail) {
            // actual kv of (subtile kvt, lane-group g, reg r) under the
            // staging permutation: kv0 + (kvt>>1)*32 + g*8 + (kvt&1)*4 + r
#pragma unroll
            for (int qt = 0; qt < 2; qt++)
#pragma unroll
                for (int kvt = 0; kvt < 4; kvt++)
#pragma unroll
                    for (int r = 0; r < 4; r++)
                        if (kv0 + (kvt >> 1) * 32 + g * 8 + (kvt & 1) * 4 + r >= NKV1)
                            s[qt][kvt][r] = -1e30f;
        }

        // p = exp2(s); pack to bf16 by truncation via v_perm; then fuse the
        // two 16-kv subtiles of each 32-window into one K=32 B-fragment.
        unsigned pw[2][4][2];
#pragma unroll
        for (int qt = 0; qt < 2; qt++)
#pragma unroll
            for (int kvt = 0; kvt < 4; kvt++) {
                const unsigned u0 = __builtin_bit_cast(unsigned, __builtin_amdgcn_exp2f(s[qt][kvt][0]));
                const unsigned u1 = __builtin_bit_cast(unsigned, __builtin_amdgcn_exp2f(s[qt][kvt][1]));
                const unsigned u2 = __builtin_bit_cast(unsigned, __builtin_amdgcn_exp2f(s[qt][kvt][2]));
                const unsigned u3 = __builtin_bit_cast(unsigned, __builtin_amdgcn_exp2f(s[qt][kvt][3]));
                pw[qt][kvt][0] = __builtin_amdgcn_perm(u1, u0, 0x07060302u);
                pw[qt][kvt][1] = __builtin_amdgcn_perm(u3, u2, 0x07060302u);
            }
        bf16x8 pf32[2][2];
#pragma unroll
        for (int qt = 0; qt < 2; qt++)
#pragma unroll
            for (int ww = 0; ww < 2; ww++) {
                uintx4 uv;
                uv[0] = pw[qt][2 * ww][0];     uv[1] = pw[qt][2 * ww][1];
                uv[2] = pw[qt][2 * ww + 1][0]; uv[3] = pw[qt][2 * ww + 1][1];
                pf32[qt][ww] = __builtin_bit_cast(bf16x8, uv);
            }

        // O^T += V^T P^T (K=32); denominator via ones-row MFMA (K=32)
        __builtin_amdgcn_s_setprio(1);
#pragma unroll
        for (int ww = 0; ww < 2; ww++) {
            bf16x8 vfr[4];
#pragma unroll
            for (int dt = 0; dt < 4; dt++)
                vfr[dt] = *(const bf16x8*)&Vs[p][dt * 16 + c][((ww * 4 + g) ^ sw) * 8];
#pragma unroll
            for (int dt = 0; dt < 4; dt++)
#pragma unroll
                for (int qt = 0; qt < 2; qt++)
                    oacc[qt][dt] = __builtin_amdgcn_mfma_f32_16x16x32_bf16(
                        vfr[dt], pf32[qt][ww], oacc[qt][dt], 0, 0, 0);
#pragma unroll
            for (int qt = 0; qt < 2; qt++)
                dacc[qt] = __builtin_amdgcn_mfma_f32_16x16x32_bf16(
                    ones8, pf32[qt][ww], dacc[qt], 0, 0, 0);
        }
        __builtin_amdgcn_s_setprio(0);
    };

    // 4-slot ring, 2 tiles per barrier period.  Tiles 0..32 (32 = tail).
    stage(0, 0, false);
    stage(1, 64, false);
    __syncthreads();
    for (int it = 0; it < 32; it += 2) {
        stage((it + 2) & 3, (it + 2) * 64, (it + 2) == 32);
        if (it + 3 <= 32) stage((it + 3) & 3, (it + 3) * 64, false);
        compute(it & 3, it * 64, false);
        compute((it + 1) & 3, (it + 1) * 64, false);
        __syncthreads();                 // staged tiles visible; reads done
    }
    compute(0, 2048, true);              // tail tile (32) in slot 0

#pragma unroll
    for (int qt = 0; qt < 2; qt++) {
        const float inv_l = 1.0f / dacc[qt][0];
        __bf16* Ob = O + ((size_t)(b * NQS + q0w + qt * 16 + c)) * DM + h * DHD;
#pragma unroll
        for (int dt = 0; dt < 4; dt++) {
            bf16x4 ob;
#pragma unroll
            for (int r = 0; r < 4; r++) ob[r] = (__bf16)(oacc[qt][dt][r] * inv_l);
            *(bf16x4*)(Ob + dt * 16 + g * 4) = ob;
        }
    }
}

// ---------------------------------------------------------------------------
extern "C" void kernel_launch(void* const* d_in, const int* in_sizes, int n_in,
                              void* d_out, int out_size, void* d_ws, size_t ws_size,
                              hipStream_t stream)
{
    const float* X      = (const float*)d_in[0];
    const float* Y      = (const float*)d_in[1];
    const float* Wq     = (const float*)d_in[2];
    const float* bq     = (const float*)d_in[3];
    const float* Wk     = (const float*)d_in[4];
    const float* bk     = (const float*)d_in[5];
    const float* Wv     = (const float*)d_in[6];
    const float* bv     = (const float*)d_in[7];
    const float* null_k = (const float*)d_in[8];
    const float* g0     = (const float*)d_in[9];
    const float* b0     = (const float*)d_in[10];
    const float* g0kv   = (const float*)d_in[11];
    const float* b0kv   = (const float*)d_in[12];
    const float* g1     = (const float*)d_in[13];
    const float* b1     = (const float*)d_in[14];
    const float* W1     = (const float*)d_in[15];
    const float* bf1    = (const float*)d_in[16];
    const float* W2     = (const float*)d_in[17];
    const float* bf2    = (const float*)d_in[18];
    float* out = (float*)d_out;

    // workspace carve (bytes).  Persistent-through-FF2 buffers FIRST so the
    // tail region (dead by FF2 time) can be reused for split-K partials.
    char* p = (char*)d_ws;
    __bf16* W2T  = (__bf16*)p; p += (size_t)4 * DM * DM * 2;          // [1024][4096]
    float*  Hres = (float*)p;  p += (size_t)ROWS * DM * 4;
    __bf16* Gbf  = (__bf16*)p; p += (size_t)ROWS * 4 * DM * 2;
    char* scratch = p;                                                // dead by FF2
    __bf16* Xn   = (__bf16*)p; p += (size_t)ROWS * DM * 2;
    __bf16* Yn   = (__bf16*)p; p += (size_t)ROWS * DM * 2;
    __bf16* WqT  = (__bf16*)p; p += (size_t)DM * DM * 2;
    __bf16* WkT  = (__bf16*)p; p += (size_t)DM * DM * 2;
    __bf16* WvT  = (__bf16*)p; p += (size_t)DM * DM * 2;
    __bf16* W1T  = (__bf16*)p; p += (size_t)4 * DM * DM * 2;          // [4096][1024]
    __bf16* Qbf  = (__bf16*)p; p += (size_t)ROWS * DM * 2;
    __bf16* Kbf  = (__bf16*)p; p += (size_t)BATCH * NKV1 * DM * 2;
    __bf16* Vt   = (__bf16*)p; p += (size_t)BATCH * NH * DHD * 2056 * 2;
    __bf16* Obf  = (__bf16*)p; p += (size_t)ROWS * DM * 2;
    __bf16* Hr   = (__bf16*)p; p += (size_t)ROWS * DM * 2;
    float* Part  = (float*)scratch;  // FF2 partials: 4 x ROWS x DM f32 = 67 MB

    // 1. LayerNorms (fused X+Y, one launch)
    ln2_to_bf16<<<2 * ROWS, 256, 0, stream>>>(X, Y, g0, b0, g0kv, b0kv, Xn, Yn);

    // 2. weight transposes (f32 -> bf16, W^T), two launches total
    transpose3_f32_bf16<<<dim3(DM / 32, DM / 32, 3), dim3(32, 8), 0, stream>>>(
        Wq, Wk, Wv, WqT, WkT, WvT);
    transpose_ffw<<<dim3(128, 32, 2), dim3(32, 8), 0, stream>>>(W1, W2, W1T, W2T);

    // 3. fused Q/K/V projections on the 8-phase BK=64 256-tile core
    g256qkv<<<dim3(64, 1, 3), 512, 0, stream>>>(
        Xn, Yn, WqT, WkT, WvT, bq, bk, bv, Qbf, Kbf, Vt);
    fill_null<<<64, 256, 0, stream>>>(null_k, Kbf, Vt);

    // 4. attention (PV at K=32 via permuted K staging)
    attn_kernel<<<dim3(512), 256, 0, stream>>>(Qbf, Kbf, Vt, Obf);

    // 5. residual + LN
    resid_ln<<<ROWS, 256, 0, stream>>>(X, Obf, g1, b1, Hres, Hr);

    // 6. FFN: FF1 (bf16 + GELU), FF2 split-K=4 partials, then reduce
    g256<0, 1, 16><<<dim3(256), 512, 0, stream>>>(
        Hr, W1T, bf1, (void*)Gbf, ROWS, 4 * DM, DM);
    g256<4, 0, 4><<<dim3(64, 1, 4), 512, 0, stream>>>(
        Gbf, W2T, bf2, (void*)Part, ROWS, DM, 4 * DM);
    ff2_reduce<<<ROWS * DM / 1024, 256, 0, stream>>>(Part, bf2, Hres, out);
}

// Round 13
// 327.130 us; speedup vs baseline: 1.0808x; 1.0264x over previous
//
#include <hip/hip_runtime.h>
#include <hip/hip_bf16.h>
#include <math.h>
#include <stdint.h>

typedef __bf16 bf16x8 __attribute__((ext_vector_type(8)));
typedef __bf16 bf16x4 __attribute__((ext_vector_type(4)));
typedef float floatx4 __attribute__((ext_vector_type(4)));
typedef short shortx4 __attribute__((ext_vector_type(4)));
typedef unsigned int uintx4 __attribute__((ext_vector_type(4)));

#define NQS   2048
#define NKVS  2048
#define NKV1  2049
#define DM    1024
#define NH    16
#define DHD   64
#define BATCH 2
#define ROWS  (BATCH * NQS)   // 4096

// async global->LDS, 16B per lane. LDS dest must be wave-uniform base + lane*16.
__device__ __forceinline__ void gld_lds16(const __bf16* gp, __bf16* lp) {
    __builtin_amdgcn_global_load_lds(
        (const __attribute__((address_space(1))) uint32_t*)(uintptr_t)gp,
        (__attribute__((address_space(3))) uint32_t*)(uintptr_t)lp,
        16, 0, 0);
}

// tanh-form GELU in exp2 domain
__device__ __forceinline__ float gelu_fast(float x) {
    const float u = x * x;
    const float e = __builtin_amdgcn_exp2f(x * (-2.3022077f + (-0.1029431f) * u));
    return x * __builtin_amdgcn_rcpf(1.0f + e);
}

// ---------------------------------------------------------------------------
// PREP megakernel: fuses 4 independent prep ops into one launch.
//   [0, 8192)            : LayerNorm rows (X then Y) -> bf16
//   [8192, 8192+3072)    : transpose Wq/Wk/Wv f32 -> bf16 W^T (32x32 tiles)
//   [+3072, +3072+8192)  : transpose W1/W2 f32 -> bf16 W^T
//   last 64              : fill null-K row + zero Vt pad columns
// 256 threads.  Shared mem union: LN uses 8 floats, transposes 32x33.
// ---------------------------------------------------------------------------
__global__ __launch_bounds__(256) void prep(
    const float* __restrict__ X, const float* __restrict__ Y,
    const float* __restrict__ g0, const float* __restrict__ b0,
    const float* __restrict__ g0kv, const float* __restrict__ b0kv,
    __bf16* __restrict__ Xn, __bf16* __restrict__ Yn,
    const float* __restrict__ Wq, const float* __restrict__ Wk,
    const float* __restrict__ Wv, __bf16* __restrict__ WqT,
    __bf16* __restrict__ WkT, __bf16* __restrict__ WvT,
    const float* __restrict__ W1, const float* __restrict__ W2,
    __bf16* __restrict__ W1T, __bf16* __restrict__ W2T,
    const float* __restrict__ null_k, __bf16* __restrict__ Kb,
    __bf16* __restrict__ Vt)
{
    __shared__ float smem[32 * 33];
    const int tid = threadIdx.x;
    int bid = blockIdx.x;

    if (bid < 2 * ROWS) {
        // ---- LayerNorm
        int row = bid;
        const float *src, *gamma, *beta; __bf16* dst;
        if (row < ROWS) { src = X; gamma = g0; beta = b0; dst = Xn; }
        else { row -= ROWS; src = Y; gamma = g0kv; beta = b0kv; dst = Yn; }
        const float4 v = ((const float4*)(src + (size_t)row * DM))[tid];
        float s  = v.x + v.y + v.z + v.w;
        float sq = v.x * v.x + v.y * v.y + v.z * v.z + v.w * v.w;
        for (int off = 1; off < 64; off <<= 1) {
            s  += __shfl_xor(s, off);
            sq += __shfl_xor(sq, off);
        }
        const int wave = tid >> 6, lane = tid & 63;
        if (lane == 0) { smem[wave * 2] = s; smem[wave * 2 + 1] = sq; }
        __syncthreads();
        s  = smem[0] + smem[2] + smem[4] + smem[6];
        sq = smem[1] + smem[3] + smem[5] + smem[7];
        const float mu  = s * (1.0f / DM);
        const float var = sq * (1.0f / DM) - mu * mu;
        const float rs  = rsqrtf(var + 1e-5f);
        const float4 gv = ((const float4*)gamma)[tid];
        const float4 bv = ((const float4*)beta)[tid];
        bf16x4 o;
        o[0] = (__bf16)((v.x - mu) * rs * gv.x + bv.x);
        o[1] = (__bf16)((v.y - mu) * rs * gv.y + bv.y);
        o[2] = (__bf16)((v.z - mu) * rs * gv.z + bv.z);
        o[3] = (__bf16)((v.w - mu) * rs * gv.w + bv.w);
        *(bf16x4*)(dst + (size_t)row * DM + tid * 4) = o;
        return;
    }
    bid -= 2 * ROWS;

    const int tx = tid & 31, ty = tid >> 5;   // (32, 8) transpose threads
    if (bid < 3072) {
        // ---- QKV weight transpose (1024x1024, 32x32 tiles)
        const int z = bid >> 10, rem = bid & 1023;
        const float* in = (z == 0) ? Wq : (z == 1) ? Wk : Wv;
        __bf16* out = (z == 0) ? WqT : (z == 1) ? WkT : WvT;
        const int c0 = (rem & 31) * 32, r0 = (rem >> 5) * 32;
#pragma unroll
        for (int i = 0; i < 4; i++)
            smem[(ty + i * 8) * 33 + tx] =
                in[(size_t)(r0 + ty + i * 8) * DM + c0 + tx];
        __syncthreads();
#pragma unroll
        for (int i = 0; i < 4; i++)
            out[(size_t)(c0 + ty + i * 8) * DM + r0 + tx] =
                (__bf16)smem[tx * 33 + ty + i * 8];
        return;
    }
    bid -= 3072;

    if (bid < 8192) {
        // ---- FFW weight transpose
        const int z = bid >> 12, rem = bid & 4095;
        const float* in; __bf16* out; int R, C, c0, r0;
        const int bx = rem & 127, by = rem >> 7;
        if (z == 0) { in = W1; out = W1T; R = DM; C = 4 * DM; c0 = bx * 32; r0 = by * 32; }
        else        { in = W2; out = W2T; R = 4 * DM; C = DM; c0 = by * 32; r0 = bx * 32; }
#pragma unroll
        for (int i = 0; i < 4; i++)
            smem[(ty + i * 8) * 33 + tx] =
                in[(size_t)(r0 + ty + i * 8) * C + c0 + tx];
        __syncthreads();
#pragma unroll
        for (int i = 0; i < 4; i++)
            out[(size_t)(c0 + ty + i * 8) * R + r0 + tx] =
                (__bf16)smem[tx * 33 + ty + i * 8];
        return;
    }
    bid -= 8192;

    // ---- fill null-K row + zero Vt pad (disjoint from qkv_gemm writes)
    const int i = bid * 256 + tid;
    if (i < BATCH * DM) {
        const int b = i >> 10, d = i & (DM - 1);
        Kb[((size_t)b * NKV1 + NKVS) * DM + d] = (__bf16)null_k[d];
    }
    if (i < BATCH * NH * DHD * 8) {  // 16384
        const int bhd = i >> 3, kvp = i & 7;
        Vt[(size_t)bhd * 2056 + 2048 + kvp] = (__bf16)0.0f;
    }
}

// ---------------------------------------------------------------------------
// Residual add + LayerNorm: Hres = X + O (f32 out), Hr = LN(Hres) (bf16 out)
// ---------------------------------------------------------------------------
__global__ __launch_bounds__(256) void resid_ln(
    const float* __restrict__ X, const __bf16* __restrict__ O,
    const float* __restrict__ gamma, const float* __restrict__ beta,
    float* __restrict__ Hres, __bf16* __restrict__ Hr)
{
    const int row = blockIdx.x;
    const int tid = threadIdx.x;
    const float4 xv = ((const float4*)(X + (size_t)row * DM))[tid];
    const bf16x4 ov = *(const bf16x4*)(O + (size_t)row * DM + tid * 4);
    float4 v;
    v.x = xv.x + (float)ov[0];
    v.y = xv.y + (float)ov[1];
    v.z = xv.z + (float)ov[2];
    v.w = xv.w + (float)ov[3];
    ((float4*)(Hres + (size_t)row * DM))[tid] = v;

    float s  = v.x + v.y + v.z + v.w;
    float sq = v.x * v.x + v.y * v.y + v.z * v.z + v.w * v.w;
    for (int off = 1; off < 64; off <<= 1) {
        s  += __shfl_xor(s, off);
        sq += __shfl_xor(sq, off);
    }
    __shared__ float red[8];
    const int wave = tid >> 6, lane = tid & 63;
    if (lane == 0) { red[wave * 2] = s; red[wave * 2 + 1] = sq; }
    __syncthreads();
    s  = red[0] + red[2] + red[4] + red[6];
    sq = red[1] + red[3] + red[5] + red[7];
    const float mu  = s * (1.0f / DM);
    const float var = sq * (1.0f / DM) - mu * mu;
    const float rs  = rsqrtf(var + 1e-5f);
    const float4 gv = ((const float4*)gamma)[tid];
    const float4 bv = ((const float4*)beta)[tid];
    bf16x4 o;
    o[0] = (__bf16)((v.x - mu) * rs * gv.x + bv.x);
    o[1] = (__bf16)((v.y - mu) * rs * gv.y + bv.y);
    o[2] = (__bf16)((v.z - mu) * rs * gv.z + bv.z);
    o[3] = (__bf16)((v.w - mu) * rs * gv.w + bv.w);
    *(bf16x4*)(Hr + (size_t)row * DM + tid * 4) = o;
}

// ---------------------------------------------------------------------------
// 256x256-tile GEMM core, m201-faithful 8-phase schedule, BK=64 (round-10).
// ---------------------------------------------------------------------------
__device__ __forceinline__ void g256_loop(
    const __bf16* __restrict__ A, const __bf16* __restrict__ Bt,
    int Kst, int kbeg, int nt, int m0, int n0,
    __bf16* sa, __bf16* sb, floatx4 (&acc)[8][4])
{
    const int tid = threadIdx.x, lane = tid & 63;
    const int g = lane >> 4, c = lane & 15;
    const int wave = tid >> 6;
    const int wm = wave >> 2, wn = wave & 3;

    const int srow = tid >> 3;
    const int jsrc = ((tid & 7) ^ (((tid >> 5) & 1) << 1)) * 8;
    const __bf16* Ag = A  + (size_t)(m0 + srow) * Kst + kbeg + jsrc;
    const __bf16* Bg = Bt + (size_t)(n0 + srow) * Kst + kbeg + jsrc;
    __bf16* la = sa + tid * 8;     // dest base (byte tid*16), linear
    __bf16* lb = sb + tid * 8;

#define STG_A(d, hf, kt) do {                                                   \
    gld_lds16(Ag + (size_t)((hf) * 128) * Kst + (kt) * 64,                      \
              la + (d) * 16384 + (hf) * 8192);                                  \
    gld_lds16(Ag + (size_t)((hf) * 128 + 64) * Kst + (kt) * 64,                 \
              la + (d) * 16384 + (hf) * 8192 + 4096);                           \
} while (0)
#define STG_B(d, hf, kt) do {                                                   \
    gld_lds16(Bg + (size_t)((hf) * 128) * Kst + (kt) * 64,                      \
              lb + (d) * 16384 + (hf) * 8192);                                  \
    gld_lds16(Bg + (size_t)((hf) * 128 + 64) * Kst + (kt) * 64,                 \
              lb + (d) * 16384 + (hf) * 8192 + 4096);                           \
} while (0)

    // prologue: all 4 halves of tile 0 (8 loads)
    STG_A(0, 0, 0); STG_A(0, 1, 0); STG_B(0, 0, 0); STG_B(0, 1, 0);

    const int flip2 = ((c >> 2) & 1) << 1;
    const __bf16* ra = sa + (wm * 128 + c) * 64;
    const __bf16* rb = sb + (wn * 64 + c) * 64;

    for (int t = 0; t < nt; t++) {
        const int d = t & 1, dn = d ^ 1;
        const bool more = (t + 1 < nt);
        if (more) STG_A(dn, 0, t + 1);            // pre-gate stage (2 loads)
        if (more) asm volatile("s_waitcnt vmcnt(2)" ::: "memory");
        else      asm volatile("s_waitcnt vmcnt(0)" ::: "memory");
        __builtin_amdgcn_sched_barrier(0);
        __builtin_amdgcn_s_barrier();             // tile t fully visible
        asm volatile("" ::: "memory");

        const __bf16* rad = ra + d * 16384;
        const __bf16* rbd = rb + d * 16384;
        bf16x8 bfr[4][2];

#pragma unroll
        for (int q = 0; q < 4; q++) {
            if (q == 0) {
#pragma unroll
                for (int n = 0; n < 4; n++)
#pragma unroll
                    for (int kk = 0; kk < 2; kk++)
                        bfr[n][kk] = *(const bf16x8*)(
                            rbd + n * 1024 + (((kk * 4 + g) ^ flip2) * 8));
            }
            bf16x8 af[2][2];
#pragma unroll
            for (int u = 0; u < 2; u++)
#pragma unroll
                for (int kk = 0; kk < 2; kk++)
                    af[u][kk] = *(const bf16x8*)(
                        rad + (q * 32 + u * 16) * 64 + (((kk * 4 + g) ^ flip2) * 8));
            if (more) {
                if (q == 0)      STG_A(dn, 1, t + 1);
                else if (q == 1) STG_B(dn, 0, t + 1);
                else if (q == 2) STG_B(dn, 1, t + 1);
            }
            if (q == 0) asm volatile("s_waitcnt lgkmcnt(8)" ::: "memory");
            __builtin_amdgcn_sched_barrier(0);
            __builtin_amdgcn_s_barrier();
            asm volatile("s_waitcnt lgkmcnt(0)" ::: "memory");
            __builtin_amdgcn_sched_barrier(0);
            __builtin_amdgcn_s_setprio(1);
#pragma unroll
            for (int kk = 0; kk < 2; kk++)
#pragma unroll
                for (int u = 0; u < 2; u++)
#pragma unroll
                    for (int n = 0; n < 4; n++)
                        acc[2 * q + u][n] = __builtin_amdgcn_mfma_f32_16x16x32_bf16(
                            af[u][kk], bfr[n][kk], acc[2 * q + u][n], 0, 0, 0);
            __builtin_amdgcn_s_setprio(0);
            __builtin_amdgcn_sched_barrier(0);
            __builtin_amdgcn_s_barrier();
            asm volatile("" ::: "memory");
        }
    }
#undef STG_A
#undef STG_B
}

// XCD-bijective block swizzle: ntot = NX*NY blocks (ntot % 8 == 0); each XCD
// gets a contiguous chunk of logical tiles for L2 reuse.
template<int NX>
__device__ __forceinline__ void g256_decode(int bid, int ntot, int& m0, int& n0)
{
    const int cpx = ntot >> 3;
    const int l = (bid & 7) * cpx + (bid >> 3);
    m0 = (l / NX) * 256;
    n0 = (l % NX) * 256;
}

// MODE 0: bf16 flat [M][N] (+bias, optional GELU).  MODE 4: split-K f32
// partials at [z][M][N] (blockIdx.z = K-slice of 1024).
template<int MODE, int ACT, int NX>
__global__ __launch_bounds__(512, 1) void g256(
    const __bf16* __restrict__ A, const __bf16* __restrict__ Bt,
    const float* __restrict__ bias, void* __restrict__ outp,
    int M, int N, int Kst)
{
    __shared__ __bf16 SA[2][256][64];
    __shared__ __bf16 SB[2][256][64];
    int m0, n0;
    g256_decode<NX>(blockIdx.x, NX * (M >> 8), m0, n0);
    const int kbeg = (MODE == 4) ? (blockIdx.z << 10) : 0;

    floatx4 acc[8][4] = {};
    g256_loop(A, Bt, Kst, kbeg, 16, m0, n0, &SA[0][0][0], &SB[0][0][0], acc);

    const int tid = threadIdx.x, lane = tid & 63, wave = tid >> 6;
    const int g = lane >> 4, c = lane & 15;
    const int wm = wave >> 2, wn = wave & 3;

    __bf16* obf = (__bf16*)outp;
    float*  of  = (float*)outp;
#pragma unroll
    for (int i = 0; i < 8; i++) {
#pragma unroll
        for (int jj = 0; jj < 4; jj++) {
            const int row = m0 + wm * 128 + i * 16 + g * 4;
            const int col = n0 + wn * 64 + jj * 16 + c;
            const float bb = (MODE == 4) ? 0.0f : bias[col];
            float xs[4];
#pragma unroll
            for (int rr = 0; rr < 4; rr++) {
                float x = acc[i][jj][rr] + bb;
                if (ACT == 1) x = gelu_fast(x);
                xs[rr] = x;
            }
            if (MODE == 0) {
#pragma unroll
                for (int rr = 0; rr < 4; rr++)
                    obf[(size_t)(row + rr) * N + col] = (__bf16)xs[rr];
            } else if (MODE == 4) {
#pragma unroll
                for (int rr = 0; rr < 4; rr++)
                    of[((size_t)blockIdx.z * M + row + rr) * N + col] = xs[rr];
            }
        }
    }
}

// Fused Q/K/V projection on the 256-tile core.  grid (64,1,3).
__global__ __launch_bounds__(512, 1) void g256qkv(
    const __bf16* __restrict__ Xn, const __bf16* __restrict__ Yn,
    const __bf16* __restrict__ WqT, const __bf16* __restrict__ WkT,
    const __bf16* __restrict__ WvT,
    const float* __restrict__ bq, const float* __restrict__ bk,
    const float* __restrict__ bv,
    __bf16* __restrict__ Qbf, __bf16* __restrict__ Kbf,
    __bf16* __restrict__ Vt)
{
    __shared__ __bf16 SA[2][256][64];
    __shared__ __bf16 SB[2][256][64];
    const int z = blockIdx.z;
    const __bf16* A    = (z == 0) ? Xn  : Yn;
    const __bf16* Bt   = (z == 0) ? WqT : (z == 1) ? WkT : WvT;
    const float*  bias = (z == 0) ? bq  : (z == 1) ? bk  : bv;

    int m0, n0;
    g256_decode<4>(blockIdx.x, 64, m0, n0);

    floatx4 acc[8][4] = {};
    g256_loop(A, Bt, DM, 0, 16, m0, n0, &SA[0][0][0], &SB[0][0][0], acc);

    const int tid = threadIdx.x, lane = tid & 63, wave = tid >> 6;
    const int g = lane >> 4, c = lane & 15;
    const int wm = wave >> 2, wn = wave & 3;

#pragma unroll
    for (int i = 0; i < 8; i++) {
#pragma unroll
        for (int jj = 0; jj < 4; jj++) {
            const int row = m0 + wm * 128 + i * 16 + g * 4;
            const int col = n0 + wn * 64 + jj * 16 + c;
            const float bb = bias[col];
            float xs[4];
#pragma unroll
            for (int rr = 0; rr < 4; rr++) xs[rr] = acc[i][jj][rr] + bb;
            if (z == 0) {
#pragma unroll
                for (int rr = 0; rr < 4; rr++)
                    Qbf[(size_t)(row + rr) * DM + col] = (__bf16)xs[rr];
            } else if (z == 1) {
#pragma unroll
                for (int rr = 0; rr < 4; rr++) {
                    const int r2 = row + rr;
                    Kbf[(size_t)(r2 + (r2 >> 11)) * DM + col] = (__bf16)xs[rr];
                }
            } else {
                const int b  = row >> 11;
                const int kv = row & 2047;
                const size_t base =
                    ((size_t)((b * NH + (col >> 6)) * DHD + (col & 63))) * 2056 + kv;
                bf16x4 pk;
                pk[0] = (__bf16)xs[0]; pk[1] = (__bf16)xs[1];
                pk[2] = (__bf16)xs[2]; pk[3] = (__bf16)xs[3];
                *(bf16x4*)(Vt + base) = pk;
            }
        }
    }
}

// ---------------------------------------------------------------------------
// FF2 split-K reduction: out = sum_z partials[z] + bias + Hres.  float4/thread.
// ---------------------------------------------------------------------------
__global__ __launch_bounds__(256) void ff2_reduce(
    const float* __restrict__ part, const float* __restrict__ bias,
    const float* __restrict__ Hres, float* __restrict__ out)
{
    const size_t f4 = (size_t)blockIdx.x * 256 + threadIdx.x;  // float4 index
    const int c4 = (int)(f4 & (DM / 4 - 1));
    const size_t stride4 = (size_t)ROWS * DM / 4;
    float4 a = ((const float4*)part)[f4];
    const float4 p1 = ((const float4*)part)[f4 + stride4];
    const float4 p2 = ((const float4*)part)[f4 + 2 * stride4];
    const float4 p3 = ((const float4*)part)[f4 + 3 * stride4];
    const float4 b  = ((const float4*)bias)[c4];
    const float4 hr = ((const float4*)Hres)[f4];
    a.x += p1.x + p2.x + p3.x + b.x + hr.x;
    a.y += p1.y + p2.y + p3.y + b.y + hr.y;
    a.z += p1.z + p2.z + p3.z + b.z + hr.z;
    a.w += p1.w + p2.w + p3.w + b.w + hr.w;
    ((float4*)out)[f4] = a;
}

// ---------------------------------------------------------------------------
// Flash attention v5 (round-11 proven): PV at mfma 16x16x32 via PERMUTED
// K-row staging; zero bank conflicts; 4-slot ring, 2 tiles per barrier;
// v_perm pack; ones-MFMA denominator; XCD-local heads.
// ---------------------------------------------------------------------------
__global__ __launch_bounds__(256, 2) void attn_kernel(
    const __bf16* __restrict__ Q, const __bf16* __restrict__ Kb,
    const __bf16* __restrict__ Vt, __bf16* __restrict__ O)
{
    __shared__ __bf16 Ks[4][64][64];   // [kv][d]   32 KB
    __shared__ __bf16 Vs[4][64][64];   // [d][kv]   32 KB

    const int tid = threadIdx.x, lane = tid & 63, w = tid >> 6;
    const int g = lane >> 4, c = lane & 15;

    const int hw   = blockIdx.x;
    const int slot = hw >> 3;
    const int hb   = (hw & 7) | ((slot >> 4) << 3);   // 0..31
    const int h = hb & 15, b = hb >> 4;
    const int q0w = (slot & 15) * 128 + w * 32;

    const float QSC = 0.03125f * 1.44269504088896f;
    bf16x8 qf[2][2];
#pragma unroll
    for (int qt = 0; qt < 2; qt++) {
        const __bf16* Qbase = Q + ((size_t)(b * NQS + q0w + qt * 16 + c)) * DM + h * DHD;
        qf[qt][0] = *(const bf16x8*)(Qbase + g * 8);
        qf[qt][1] = *(const bf16x8*)(Qbase + 32 + g * 8);
#pragma unroll
        for (int e = 0; e < 8; e++) {
            qf[qt][0][e] = (__bf16)((float)qf[qt][0][e] * QSC);
            qf[qt][1][e] = (__bf16)((float)qf[qt][1][e] * QSC);
        }
    }

    // ones A-fragment for the denominator MFMA (K=32)
    bf16x8 ones8;
#pragma unroll
    for (int e = 0; e < 8; e++) ones8[e] = (__bf16)1.0f;

    floatx4 dacc[2] = {};        // denominator accumulators (rows identical)
    floatx4 oacc[2][4] = {};

    const int srow = tid >> 3;                    // LDS row 0..31 (and +32)
    const int schk = (tid & 7) ^ (srow & 7);      // swizzled 16B source chunk
    // permuted K source row: LDS row i holds actual kv offset a(i)
    const int sr4 = srow & 15, st0 = srow >> 4;
    const int prow = ((sr4 >> 2) << 3) + (st0 << 2) + (sr4 & 3);   // 0..31
    const __bf16* Kg  = Kb + (size_t)b * NKV1 * DM + h * DHD + schk * 8;
    const __bf16* Vg  = Vt + ((size_t)(b * NH + h) * DHD + srow) * 2056;
    const __bf16* Vg2 = Vg + (size_t)32 * 2056;
    const int vcol0 = schk * 8;

    auto stage = [&](int p, int kv0, bool tail) {
        __bf16* kd0 = &Ks[p][0][0]  + tid * 8;
        __bf16* kd1 = &Ks[p][32][0] + tid * 8;
        __bf16* vd0 = &Vs[p][0][0]  + tid * 8;
        __bf16* vd1 = &Vs[p][32][0] + tid * 8;
        if (!tail) {
            gld_lds16(Kg + (size_t)(kv0 + prow) * DM, kd0);
            gld_lds16(Kg + (size_t)(kv0 + prow + 32) * DM, kd1);
            gld_lds16(Vg + kv0 + vcol0, vd0);
            gld_lds16(Vg2 + kv0 + vcol0, vd1);
        } else {
            const int r0 = min(kv0 + prow, NKVS);
            const int r1 = min(kv0 + prow + 32, NKVS);
            const int vc = min(kv0 + vcol0, NKVS);
            gld_lds16(Kg + (size_t)r0 * DM, kd0);
            gld_lds16(Kg + (size_t)r1 * DM, kd1);
            gld_lds16(Vg + vc, vd0);
            gld_lds16(Vg2 + vc, vd1);
        }
    };

    auto compute = [&](int p, int kv0, bool tail) {
        floatx4 s[2][4];
#pragma unroll
        for (int qt = 0; qt < 2; qt++)
#pragma unroll
            for (int kvt = 0; kvt < 4; kvt++)
#pragma unroll
                for (int r = 0; r < 4; r++) s[qt][kvt][r] = -6.0f;

        const int sw = c & 7;
        __builtin_amdgcn_s_setprio(1);
#pragma unroll
        for (int kvt = 0; kvt < 4; kvt++) {
            const bf16x8 kf0 = *(const bf16x8*)&Ks[p][kvt * 16 + c][(g ^ sw) * 8];
            const bf16x8 kf1 = *(const bf16x8*)&Ks[p][kvt * 16 + c][((4 | g) ^ sw) * 8];
#pragma unroll
            for (int qt = 0; qt < 2; qt++) {
                s[qt][kvt] = __builtin_amdgcn_mfma_f32_16x16x32_bf16(kf0, qf[qt][0], s[qt][kvt], 0, 0, 0);
                s[qt][kvt] = __builtin_amdgcn_mfma_f32_16x16x32_bf16(kf1, qf[qt][1], s[qt][kvt], 0, 0, 0);
            }
        }
        __builtin_amdgcn_s_setprio(0);

        if (tail) {
            // actual kv of (subtile kvt, lane-group g, reg r) under the
            // staging permutation: kv0 + (kvt>>1)*32 + g*8 + (kvt&1)*4 + r
#pragma unroll
            for (int qt = 0; qt < 2; qt++)
#pragma unroll
                for (int kvt = 0; kvt < 4; kvt++)
#pragma unroll
                    for (int r = 0; r < 4; r++)
                        if (kv0 + (kvt >> 1) * 32 + g * 8 + (kvt & 1) * 4 + r >= NKV1)
                            s[qt][kvt][r] = -1e30f;
        }

        // p = exp2(s); pack to bf16 by truncation via v_perm; then fuse the
        // two 16-kv subtiles of each 32-window into one K=32 B-fragment.
        unsigned pw[2][4][2];
#pragma unroll
        for (int qt = 0; qt < 2; qt++)
#pragma unroll
            for (int kvt = 0; kvt < 4; kvt++) {
                const unsigned u0 = __builtin_bit_cast(unsigned, __builtin_amdgcn_exp2f(s[qt][kvt][0]));
                const unsigned u1 = __builtin_bit_cast(unsigned, __builtin_amdgcn_exp2f(s[qt][kvt][1]));
                const unsigned u2 = __builtin_bit_cast(unsigned, __builtin_amdgcn_exp2f(s[qt][kvt][2]));
                const unsigned u3 = __builtin_bit_cast(unsigned, __builtin_amdgcn_exp2f(s[qt][kvt][3]));
                pw[qt][kvt][0] = __builtin_amdgcn_perm(u1, u0, 0x07060302u);
                pw[qt][kvt][1] = __builtin_amdgcn_perm(u3, u2, 0x07060302u);
            }
        bf16x8 pf32[2][2];
#pragma unroll
        for (int qt = 0; qt < 2; qt++)
#pragma unroll
            for (int ww = 0; ww < 2; ww++) {
                uintx4 uv;
                uv[0] = pw[qt][2 * ww][0];     uv[1] = pw[qt][2 * ww][1];
                uv[2] = pw[qt][2 * ww + 1][0]; uv[3] = pw[qt][2 * ww + 1][1];
                pf32[qt][ww] = __builtin_bit_cast(bf16x8, uv);
            }

        // O^T += V^T P^T (K=32); denominator via ones-row MFMA (K=32)
        __builtin_amdgcn_s_setprio(1);
#pragma unroll
        for (int ww = 0; ww < 2; ww++) {
            bf16x8 vfr[4];
#pragma unroll
            for (int dt = 0; dt < 4; dt++)
                vfr[dt] = *(const bf16x8*)&Vs[p][dt * 16 + c][((ww * 4 + g) ^ sw) * 8];
#pragma unroll
            for (int dt = 0; dt < 4; dt++)
#pragma unroll
                for (int qt = 0; qt < 2; qt++)
                    oacc[qt][dt] = __builtin_amdgcn_mfma_f32_16x16x32_bf16(
                        vfr[dt], pf32[qt][ww], oacc[qt][dt], 0, 0, 0);
#pragma unroll
            for (int qt = 0; qt < 2; qt++)
                dacc[qt] = __builtin_amdgcn_mfma_f32_16x16x32_bf16(
                    ones8, pf32[qt][ww], dacc[qt], 0, 0, 0);
        }
        __builtin_amdgcn_s_setprio(0);
    };

    // 4-slot ring, 2 tiles per barrier period.  Tiles 0..32 (32 = tail).
    stage(0, 0, false);
    stage(1, 64, false);
    __syncthreads();
    for (int it = 0; it < 32; it += 2) {
        stage((it + 2) & 3, (it + 2) * 64, (it + 2) == 32);
        if (it + 3 <= 32) stage((it + 3) & 3, (it + 3) * 64, false);
        compute(it & 3, it * 64, false);
        compute((it + 1) & 3, (it + 1) * 64, false);
        __syncthreads();                 // staged tiles visible; reads done
    }
    compute(0, 2048, true);              // tail tile (32) in slot 0

#pragma unroll
    for (int qt = 0; qt < 2; qt++) {
        const float inv_l = 1.0f / dacc[qt][0];
        __bf16* Ob = O + ((size_t)(b * NQS + q0w + qt * 16 + c)) * DM + h * DHD;
#pragma unroll
        for (int dt = 0; dt < 4; dt++) {
            bf16x4 ob;
#pragma unroll
            for (int r = 0; r < 4; r++) ob[r] = (__bf16)(oacc[qt][dt][r] * inv_l);
            *(bf16x4*)(Ob + dt * 16 + g * 4) = ob;
        }
    }
}

// ---------------------------------------------------------------------------
extern "C" void kernel_launch(void* const* d_in, const int* in_sizes, int n_in,
                              void* d_out, int out_size, void* d_ws, size_t ws_size,
                              hipStream_t stream)
{
    const float* X      = (const float*)d_in[0];
    const float* Y      = (const float*)d_in[1];
    const float* Wq     = (const float*)d_in[2];
    const float* bq     = (const float*)d_in[3];
    const float* Wk     = (const float*)d_in[4];
    const float* bk     = (const float*)d_in[5];
    const float* Wv     = (const float*)d_in[6];
    const float* bv     = (const float*)d_in[7];
    const float* null_k = (const float*)d_in[8];
    const float* g0     = (const float*)d_in[9];
    const float* b0     = (const float*)d_in[10];
    const float* g0kv   = (const float*)d_in[11];
    const float* b0kv   = (const float*)d_in[12];
    const float* g1     = (const float*)d_in[13];
    const float* b1     = (const float*)d_in[14];
    const float* W1     = (const float*)d_in[15];
    const float* bf1    = (const float*)d_in[16];
    const float* W2     = (const float*)d_in[17];
    const float* bf2    = (const float*)d_in[18];
    float* out = (float*)d_out;

    // workspace carve (bytes).  Persistent-through-FF2 buffers FIRST so the
    // tail region (dead by FF2 time) can be reused for split-K partials.
    char* p = (char*)d_ws;
    __bf16* W2T  = (__bf16*)p; p += (size_t)4 * DM * DM * 2;          // [1024][4096]
    float*  Hres = (float*)p;  p += (size_t)ROWS * DM * 4;
    __bf16* Gbf  = (__bf16*)p; p += (size_t)ROWS * 4 * DM * 2;
    char* scratch = p;                                                // dead by FF2
    __bf16* Xn   = (__bf16*)p; p += (size_t)ROWS * DM * 2;
    __bf16* Yn   = (__bf16*)p; p += (size_t)ROWS * DM * 2;
    __bf16* WqT  = (__bf16*)p; p += (size_t)DM * DM * 2;
    __bf16* WkT  = (__bf16*)p; p += (size_t)DM * DM * 2;
    __bf16* WvT  = (__bf16*)p; p += (size_t)DM * DM * 2;
    __bf16* W1T  = (__bf16*)p; p += (size_t)4 * DM * DM * 2;          // [4096][1024]
    __bf16* Qbf  = (__bf16*)p; p += (size_t)ROWS * DM * 2;
    __bf16* Kbf  = (__bf16*)p; p += (size_t)BATCH * NKV1 * DM * 2;
    __bf16* Vt   = (__bf16*)p; p += (size_t)BATCH * NH * DHD * 2056 * 2;
    __bf16* Obf  = (__bf16*)p; p += (size_t)ROWS * DM * 2;
    __bf16* Hr   = (__bf16*)p; p += (size_t)ROWS * DM * 2;
    float* Part  = (float*)scratch;  // FF2 partials: 4 x ROWS x DM f32 = 67 MB

    // 1. PREP megakernel: LN(X,Y) + all weight transposes + null-K/V-pad fill
    //    (fill is disjoint from qkv writes -> safe to run before qkv)
    prep<<<2 * ROWS + 3072 + 8192 + 64, 256, 0, stream>>>(
        X, Y, g0, b0, g0kv, b0kv, Xn, Yn,
        Wq, Wk, Wv, WqT, WkT, WvT,
        W1, W2, W1T, W2T,
        null_k, Kbf, Vt);

    // 2. fused Q/K/V projections on the 8-phase BK=64 256-tile core
    g256qkv<<<dim3(64, 1, 3), 512, 0, stream>>>(
        Xn, Yn, WqT, WkT, WvT, bq, bk, bv, Qbf, Kbf, Vt);

    // 3. attention (PV at K=32 via permuted K staging)
    attn_kernel<<<dim3(512), 256, 0, stream>>>(Qbf, Kbf, Vt, Obf);

    // 4. residual + LN
    resid_ln<<<ROWS, 256, 0, stream>>>(X, Obf, g1, b1, Hres, Hr);

    // 5. FFN: FF1 (bf16 + GELU), FF2 split-K=4 partials, then reduce
    g256<0, 1, 16><<<dim3(256), 512, 0, stream>>>(
        Hr, W1T, bf1, (void*)Gbf, ROWS, 4 * DM, DM);
    g256<4, 0, 4><<<dim3(64, 1, 4), 512, 0, stream>>>(
        Gbf, W2T, bf2, (void*)Part, ROWS, DM, 4 * DM);
    ff2_reduce<<<ROWS * DM / 1024, 256, 0, stream>>>(Part, bf2, Hres, out);
}